// Round 5
// baseline (256.409 us; speedup 1.0000x reference)
//
#include <hip/hip_runtime.h>
#include <hip/hip_bf16.h>

// x(2,4096,768) -> LN -> QKV proj -> 8-head attention (d=64) -> Wo.
// Inputs fp32 (runtime-detected); internal pipeline bf16.
// B=2, L=4096, DIM=768, HEADS=8, DHEAD=64, INNER=512.
// 4 dispatches: prep (LN + W^T + flag), QKV GEMM (Q pre-scaled, V written
// transposed straight to vtg), attention (v11 = v10 compute with 64-row
// blocks / 16 q-rows per wave / NO split-K: LDS 69.6->26.1 KB, grid 512->1024
// -> 4 blocks/CU, 16 waves/CU; direct epilogue), output GEMM.

typedef __bf16 bf16_t;
typedef __bf16 bf16x4 __attribute__((ext_vector_type(4)));
typedef __bf16 bf16x8 __attribute__((ext_vector_type(8)));
typedef float f32x4 __attribute__((ext_vector_type(4)));
typedef unsigned int u32x2 __attribute__((ext_vector_type(2)));

#define MFMA16(a, b, c) __builtin_amdgcn_mfma_f32_16x16x32_bf16((a), (b), (c), 0, 0, 0)

// 0.125 (softmax scale^2) * log2(e): scores come out of QK^T in log2 units.
#define QSCALE 0.18033688011112042f

// async global->LDS, 16 B per lane; LDS dst = wave-uniform base + lane*16.
#define GLDS(gp, lp)                                                          \
    __builtin_amdgcn_global_load_lds(                                         \
        (const __attribute__((address_space(1))) void*)(gp),                  \
        (__attribute__((address_space(3))) void*)(lp), 16, 0, 0)

// ---------------------------------------------------------------------------
// Per-wave input-dtype detect: 1 = fp32, 0 = bf16. 128 L2-hot words.
// ---------------------------------------------------------------------------
__device__ __forceinline__ int detect_f32(const unsigned int* __restrict__ xw) {
    const int l = threadIdx.x & 63;
    int cnt = 0;
#pragma unroll
    for (int j = 0; j < 2; ++j) {
        const unsigned int e = (xw[l * 2 + j] >> 7) & 0xFF;
        cnt += (e >= 100 && e <= 140) ? 1 : 0;
    }
#pragma unroll
    for (int off = 1; off < 64; off <<= 1) cnt += __shfl_xor(cnt, off, 64);
    return cnt < 64;
}

// ---------------------------------------------------------------------------
// prep: blocks 0..2047 = LayerNorm (4 rows each, wave-per-row);
// blocks 2048..2431 = 64x64 transpose tiles of Wq/Wkv/Wo -> bf16 W^T.
// ---------------------------------------------------------------------------
__global__ __launch_bounds__(256) void prep_kernel(
    const void* __restrict__ xv, const void* __restrict__ gv,
    const void* __restrict__ bv, const void* __restrict__ wq,
    const void* __restrict__ wkv, const void* __restrict__ wo,
    bf16_t* __restrict__ xn, bf16_t* __restrict__ WqkvT, bf16_t* __restrict__ WoT,
    int* __restrict__ flag) {
    const int f32 = detect_f32((const unsigned int*)xv);
    const int bid = blockIdx.x;
    const int t = threadIdx.x;
    if (bid == 0 && t == 0) *flag = f32;

    __shared__ bf16_t Ts[64 * 68];

    if (bid < 2048) {
        const int lane = t & 63;
        const int row = bid * 4 + (t >> 6);
        const int c0 = lane * 12;
        float v[12];
        if (f32) {
            const float* xr = (const float*)xv + (size_t)row * 768 + c0;
#pragma unroll
            for (int i = 0; i < 3; ++i) {
                const float4 q = *(const float4*)(xr + i * 4);
                v[i * 4] = q.x; v[i * 4 + 1] = q.y;
                v[i * 4 + 2] = q.z; v[i * 4 + 3] = q.w;
            }
        } else {
            const bf16_t* xr = (const bf16_t*)xv + (size_t)row * 768 + c0;
#pragma unroll
            for (int i = 0; i < 3; ++i) {
                const bf16x4 q = *(const bf16x4*)(xr + i * 4);
#pragma unroll
                for (int j = 0; j < 4; ++j) v[i * 4 + j] = (float)q[j];
            }
        }
        float s = 0.f, sq = 0.f;
#pragma unroll
        for (int j = 0; j < 12; ++j) { s += v[j]; sq += v[j] * v[j]; }
#pragma unroll
        for (int off = 1; off < 64; off <<= 1) {
            s += __shfl_xor(s, off, 64);
            sq += __shfl_xor(sq, off, 64);
        }
        const float mu = s * (1.0f / 768.0f);
        const float var = sq * (1.0f / 768.0f) - mu * mu;
        const float rstd = rsqrtf(var + 1e-5f);

        bf16_t* xo = xn + (size_t)row * 768 + c0;
#pragma unroll
        for (int i = 0; i < 3; ++i) {
            bf16x4 o;
#pragma unroll
            for (int j = 0; j < 4; ++j) {
                const int c = c0 + i * 4 + j;
                const float gc = f32 ? ((const float*)gv)[c] : (float)((const bf16_t*)gv)[c];
                const float bc = f32 ? ((const float*)bv)[c] : (float)((const bf16_t*)bv)[c];
                o[j] = (bf16_t)((v[i * 4 + j] - mu) * rstd * gc + bc);
            }
            *(bf16x4*)(xo + i * 4) = o;
        }
        return;
    }

    int idx = bid - 2048;
    const void* in;
    bf16_t* out;
    int R, C, cx, ry;
    if (idx < 96) {                       // Wq: 768x512 -> WqkvT[0..511][768]
        in = wq; out = WqkvT; R = 768; C = 512;
        cx = idx & 7; ry = idx >> 3;
    } else if (idx < 288) {               // Wkv: 768x1024 -> WqkvT[512..1535][768]
        idx -= 96;
        in = wkv; out = WqkvT + (size_t)512 * 768; R = 768; C = 1024;
        cx = idx & 15; ry = idx >> 4;
    } else {                              // Wo: 512x768 -> WoT[768][512]
        idx -= 288;
        in = wo; out = WoT; R = 512; C = 768;
        cx = idx % 12; ry = idx / 12;
    }
    const int r0 = ry * 64, c0 = cx * 64;
    {
        const int r = t >> 2, c = (t & 3) * 16;
        if (f32) {
            const float* src = (const float*)in + (size_t)(r0 + r) * C + c0 + c;
#pragma unroll
            for (int i = 0; i < 16; i += 4) {
                const float4 q = *(const float4*)(src + i);
                Ts[r * 68 + c + i] = (bf16_t)q.x;
                Ts[r * 68 + c + i + 1] = (bf16_t)q.y;
                Ts[r * 68 + c + i + 2] = (bf16_t)q.z;
                Ts[r * 68 + c + i + 3] = (bf16_t)q.w;
            }
        } else {
            const bf16_t* src = (const bf16_t*)in + (size_t)(r0 + r) * C + c0 + c;
            *(bf16x8*)&Ts[r * 68 + c] = *(const bf16x8*)src;
            *(bf16x8*)&Ts[r * 68 + c + 8] = *(const bf16x8*)(src + 8);
        }
    }
    __syncthreads();
    {
        const int oc = t >> 2, seg = (t & 3) * 16;
        bf16x8 v0, v1;
#pragma unroll
        for (int j = 0; j < 8; ++j) v0[j] = Ts[(seg + j) * 68 + oc];
#pragma unroll
        for (int j = 0; j < 8; ++j) v1[j] = Ts[(seg + 8 + j) * 68 + oc];
        bf16_t* dst = out + (size_t)(c0 + oc) * R + r0 + seg;
        *(bf16x8*)dst = v0;
        *(bf16x8*)(dst + 8) = v1;
    }
}

// ---------------------------------------------------------------------------
// QKV GEMM (m97-style): qkv[M][1536] = xn @ WqkvT^T. 128x128 tile, BK=32,
// global_load_lds width 16. Epilogue: Q cols (<512) scaled by QSCALE; K cols
// written to qkv; V cols (>=1024) written TRANSPOSED to vtg[bh][d][tok].
// ---------------------------------------------------------------------------
__global__ __launch_bounds__(256) void qkv_gemm(const bf16_t* __restrict__ A,
                                                const bf16_t* __restrict__ BT,
                                                bf16_t* __restrict__ qkv,
                                                bf16_t* __restrict__ vtg,
                                                int M, int N, int K) {
    const int m0 = blockIdx.y * 128;
    const int n0 = blockIdx.x * 128;
    __shared__ bf16_t As[128 * 32];
    __shared__ bf16_t Bs[128 * 32];

    const int t = threadIdx.x;
    const int lane = t & 63;
    const int w = t >> 6;
    const int wm = (w >> 1) * 64;
    const int wn = (w & 1) * 64;
    const int quad = lane >> 4;
    const int cl = lane & 15;

    f32x4 acc[4][4];
    const f32x4 z4 = {0.f, 0.f, 0.f, 0.f};
#pragma unroll
    for (int mi = 0; mi < 4; ++mi)
#pragma unroll
        for (int ni = 0; ni < 4; ++ni) acc[mi][ni] = z4;

    const int r0 = lane >> 2;
    const int c0 = (lane & 3) * 8;
    const bf16_t* AgL = A + (size_t)(m0 + w * 32 + r0) * K + c0;
    const bf16_t* AgH = A + (size_t)(m0 + w * 32 + 16 + r0) * K + c0;
    const bf16_t* BgL = BT + (size_t)(n0 + w * 32 + r0) * K + c0;
    const bf16_t* BgH = BT + (size_t)(n0 + w * 32 + 16 + r0) * K + c0;
    bf16_t* AdL = &As[(w * 32) * 32];
    bf16_t* AdH = &As[(w * 32 + 16) * 32];
    bf16_t* BdL = &Bs[(w * 32) * 32];
    bf16_t* BdH = &Bs[(w * 32 + 16) * 32];

    for (int kt = 0; kt < K; kt += 32) {
        __syncthreads();
        GLDS(AgL + kt, AdL);
        GLDS(AgH + kt, AdH);
        GLDS(BgL + kt, BdL);
        GLDS(BgH + kt, BdH);
        __syncthreads();  // drains vmcnt(0): LDS tiles complete

        const int ko = quad * 8;
        bf16x8 af[4], bfr[4];
#pragma unroll
        for (int mi = 0; mi < 4; ++mi)
            af[mi] = *(const bf16x8*)&As[(wm + mi * 16 + cl) * 32 + ko];
#pragma unroll
        for (int ni = 0; ni < 4; ++ni)
            bfr[ni] = *(const bf16x8*)&Bs[(wn + ni * 16 + cl) * 32 + ko];
#pragma unroll
        for (int mi = 0; mi < 4; ++mi)
#pragma unroll
            for (int ni = 0; ni < 4; ++ni)
                acc[mi][ni] = MFMA16(af[mi], bfr[ni], acc[mi][ni]);
    }

    if (n0 >= 1024) {
        // ---- V tile: write transposed to vtg[(b*8+h)*64+d][tok] ----
        const int b = m0 >> 12;
#pragma unroll
        for (int mi = 0; mi < 4; ++mi) {
#pragma unroll
            for (int ni = 0; ni < 4; ++ni) {
                const int tok = (m0 & 4095) + wm + mi * 16 + quad * 4;
                const int dl = n0 + wn + ni * 16 + cl - 1024;   // 0..511
                bf16x4 pk;
#pragma unroll
                for (int r4 = 0; r4 < 4; ++r4) pk[r4] = (bf16_t)acc[mi][ni][r4];
                *(bf16x4*)(vtg + ((size_t)(b * 8 + (dl >> 6)) * 64 + (dl & 63)) * 4096 +
                           tok) = pk;
            }
        }
    } else {
        const float sc = (n0 < 512) ? QSCALE : 1.0f;
#pragma unroll
        for (int mi = 0; mi < 4; ++mi) {
#pragma unroll
            for (int ni = 0; ni < 4; ++ni) {
#pragma unroll
                for (int r4 = 0; r4 < 4; ++r4) {
                    const int row = m0 + wm + mi * 16 + quad * 4 + r4;
                    const int col = n0 + wn + ni * 16 + cl;
                    qkv[(size_t)row * N + col] = (bf16_t)(acc[mi][ni][r4] * sc);
                }
            }
        }
    }
}

// ---------------------------------------------------------------------------
// GEMM, 128(M)x64(N) 2-wave blocks for the final projection. Output fp32 or
// bf16 per *out_flag.
// ---------------------------------------------------------------------------
__global__ __launch_bounds__(128) void gemm_bt64(const bf16_t* __restrict__ A,
                                                 const bf16_t* __restrict__ BT,
                                                 void* __restrict__ C,
                                                 int M, int N, int K,
                                                 const int* __restrict__ out_flag) {
    const int m0 = blockIdx.y * 128;
    const int n0 = blockIdx.x * 64;
    __shared__ bf16_t As[128 * 32];
    __shared__ bf16_t Bs[64 * 32];

    const int t = threadIdx.x;
    const int lane = t & 63;
    const int w = t >> 6;  // 0..1
    const int quad = lane >> 4;
    const int cl = lane & 15;

    f32x4 acc[4][4];
    const f32x4 z4 = {0.f, 0.f, 0.f, 0.f};
#pragma unroll
    for (int mi = 0; mi < 4; ++mi)
#pragma unroll
        for (int ni = 0; ni < 4; ++ni) acc[mi][ni] = z4;

    const int r0 = lane >> 2;
    const int c0 = (lane & 3) * 8;
    const bf16_t* Ag = A + (size_t)(m0 + w * 64 + r0) * K + c0;
    const bf16_t* Bg = BT + (size_t)(n0 + w * 32 + r0) * K + c0;
    bf16_t* Ad = &As[(w * 64) * 32];
    bf16_t* Bd = &Bs[(w * 32) * 32];

    for (int kt = 0; kt < K; kt += 32) {
        __syncthreads();
#pragma unroll
        for (int i = 0; i < 4; ++i) GLDS(Ag + kt + (size_t)i * 16 * K, Ad + i * 512);
#pragma unroll
        for (int i = 0; i < 2; ++i) GLDS(Bg + kt + (size_t)i * 16 * K, Bd + i * 512);
        __syncthreads();

        const int ko = quad * 8;
        bf16x8 af[4], bfr[4];
#pragma unroll
        for (int mi = 0; mi < 4; ++mi)
            af[mi] = *(const bf16x8*)&As[(w * 64 + mi * 16 + cl) * 32 + ko];
#pragma unroll
        for (int ni = 0; ni < 4; ++ni)
            bfr[ni] = *(const bf16x8*)&Bs[(ni * 16 + cl) * 32 + ko];
#pragma unroll
        for (int mi = 0; mi < 4; ++mi)
#pragma unroll
            for (int ni = 0; ni < 4; ++ni)
                acc[mi][ni] = MFMA16(af[mi], bfr[ni], acc[mi][ni]);
    }

    const int f32out = *out_flag;
#pragma unroll
    for (int mi = 0; mi < 4; ++mi) {
#pragma unroll
        for (int ni = 0; ni < 4; ++ni) {
#pragma unroll
            for (int r4 = 0; r4 < 4; ++r4) {
                const int row = m0 + w * 64 + mi * 16 + quad * 4 + r4;
                const int col = n0 + ni * 16 + cl;
                if (f32out)
                    ((float*)C)[(size_t)row * N + col] = acc[mi][ni][r4];
                else
                    ((bf16_t*)C)[(size_t)row * N + col] = (bf16_t)acc[mi][ni][r4];
            }
        }
    }
}

// ---------------------------------------------------------------------------
// Flash attention v11: 64-row q blocks, 4 waves x 16 q-rows, full token range
// per block (NO split-K). LDS = Ps(4x16x68) + Ks(64x68) + Vs(64x68) = 26.1 KB
// -> 4 blocks/CU, 16 waves/CU (2x v10 occupancy). Per-lane MFMA mappings are
// exactly v10's with the rt/kh dimensions removed. Q staged via GLDS into Ks
// (dead until loop). Direct divided epilogue store.
// ---------------------------------------------------------------------------
__global__ __launch_bounds__(256, 4) void attn_kernel(const bf16_t* __restrict__ qkv,
                                                      const bf16_t* __restrict__ vtg,
                                                      bf16_t* __restrict__ ao) {
    const int qt = blockIdx.x;    // 0..63  (64-row q tile)
    const int bh = blockIdx.y;    // 0..15
    const int b = bh >> 3, h = bh & 7;
    const int q0 = qt * 64;

    __shared__ bf16_t Ps[4][16 * 68];   // per-wave P band: 16 q x 64 tok (+pad)
    __shared__ bf16_t Ks[64 * 68];      // [tok][d] stride 68; also Q staging
    __shared__ bf16_t Vs[64 * 68];      // [d][tok] stride 68

    const int t = threadIdx.x;
    const int lane = t & 63;
    const int w = t >> 6;         // 0..3: 16-row q subtile
    const int quad = lane >> 4;
    const int cl = lane & 15;

    const size_t rowbase = (size_t)b * 4096;
    const int qcol = h * 64;
    const int kcol = 512 + h * 64;

    // ---- stage Q (64x64, pre-scaled) via GLDS into Ks linear [row][64] ----
    bf16_t* Qtr = &Ks[0];
    {
        const bf16_t* qsrc = qkv + (rowbase + q0 + w * 16) * 1536 + qcol;
#pragma unroll
        for (int i = 0; i < 2; ++i)
            GLDS(qsrc + (size_t)(i * 8 + (lane >> 3)) * 1536 + (lane & 7) * 8,
                 Qtr + (w * 16 + i * 8) * 64);
    }

    // ---- staging ptrs: thread t covers rows sr2 and sr2+32, 16B seg ----
    const int sr2 = t >> 3;       // 0..31
    const int sh2 = (t & 7) * 8;  // 0..56 elems
    const bf16_t* kgp = qkv + (rowbase + sr2) * 1536 + kcol + sh2;
    const bf16_t* vgp = vtg + ((size_t)bh * 64 + sr2) * 4096 + sh2;

    bf16x8 kreg[2], vreg[2];
    {   // tile 0 -> regs (in flight across the Q-staging barrier)
        kreg[0] = *(const bf16x8*)(kgp);
        kreg[1] = *(const bf16x8*)(kgp + (size_t)32 * 1536);
        vreg[0] = *(const bf16x8*)(vgp);
        vreg[1] = *(const bf16x8*)(vgp + (size_t)32 * 4096);
    }

    __syncthreads();  // Q staged (vmcnt drained)

    bf16x8 aq[2];
#pragma unroll
    for (int hh = 0; hh < 2; ++hh)
        aq[hh] = *(const bf16x8*)&Qtr[(w * 16 + cl) * 64 + hh * 32 + quad * 8];

    bf16x8 ones;
#pragma unroll
    for (int e = 0; e < 8; ++e) ones[e] = (bf16_t)1.0f;

    const f32x4 z4 = {0.f, 0.f, 0.f, 0.f};
    f32x4 o[4];
    f32x4 l_acc = z4;
#pragma unroll
    for (int ni = 0; ni < 4; ++ni) o[ni] = z4;

    for (int it = 0; it < 64; ++it) {
        __syncthreads();  // prior-iter frag reads (and aq reads) complete
        *(bf16x8*)&Ks[sr2 * 68 + sh2] = kreg[0];
        *(bf16x8*)&Ks[(sr2 + 32) * 68 + sh2] = kreg[1];
        *(bf16x8*)&Vs[sr2 * 68 + sh2] = vreg[0];
        *(bf16x8*)&Vs[(sr2 + 32) * 68 + sh2] = vreg[1];
        __syncthreads();

        if (it < 63) {   // prefetch next tile (latency hidden under compute)
            const size_t ko = (size_t)(it + 1) * 64;
            kreg[0] = *(const bf16x8*)(kgp + ko * 1536);
            kreg[1] = *(const bf16x8*)(kgp + (ko + 32) * 1536);
            vreg[0] = *(const bf16x8*)(vgp + ko);
            vreg[1] = *(const bf16x8*)(vgp + (size_t)32 * 4096 + ko);
        }

        const int ko2 = quad * 8;
        // ---- QK^T (S^T tiles: rows=tok, cols=q) + exp + packed P store ----
        __builtin_amdgcn_s_setprio(1);
#pragma unroll
        for (int ni = 0; ni < 4; ++ni) {
            const bf16x8 kb0 = *(const bf16x8*)&Ks[(ni * 16 + cl) * 68 + ko2];
            const bf16x8 kb1 = *(const bf16x8*)&Ks[(ni * 16 + cl) * 68 + 32 + ko2];
            f32x4 s = z4;
            s = MFMA16(kb0, aq[0], s);
            s = MFMA16(kb1, aq[1], s);
            const float e0 = __builtin_amdgcn_exp2f(s[0]);
            const float e1 = __builtin_amdgcn_exp2f(s[1]);
            const float e2 = __builtin_amdgcn_exp2f(s[2]);
            const float e3 = __builtin_amdgcn_exp2f(s[3]);
            u32x2 pk;
            asm("v_cvt_pk_bf16_f32 %0, %1, %2" : "=v"(pk[0]) : "v"(e0), "v"(e1));
            asm("v_cvt_pk_bf16_f32 %0, %1, %2" : "=v"(pk[1]) : "v"(e2), "v"(e3));
            *(u32x2*)&Ps[w][cl * 68 + ni * 16 + quad * 4] = pk;
        }
        __builtin_amdgcn_s_setprio(0);

        // ---- PV + l (P band is per-wave private; no barrier needed) ----
        const bf16x8 p0 = *(const bf16x8*)&Ps[w][cl * 68 + ko2];
        const bf16x8 p1 = *(const bf16x8*)&Ps[w][cl * 68 + 32 + ko2];
        __builtin_amdgcn_s_setprio(1);
#pragma unroll
        for (int ni = 0; ni < 4; ++ni) {
            const bf16x8 vb0 = *(const bf16x8*)&Vs[(ni * 16 + cl) * 68 + ko2];
            const bf16x8 vb1 = *(const bf16x8*)&Vs[(ni * 16 + cl) * 68 + 32 + ko2];
            o[ni] = MFMA16(p0, vb0, o[ni]);
            o[ni] = MFMA16(p1, vb1, o[ni]);
        }
        l_acc = MFMA16(p0, ones, l_acc);
        l_acc = MFMA16(p1, ones, l_acc);
        __builtin_amdgcn_s_setprio(0);
    }

    // ---- epilogue: q-row = w*16 + quad*4 + r4 (C-layout), d = ni*16+cl ----
#pragma unroll
    for (int r4 = 0; r4 < 4; ++r4) {
        const int row = q0 + w * 16 + quad * 4 + r4;
        const float inv = 1.0f / l_acc[r4];
        bf16_t* op = ao + (rowbase + row) * 512 + qcol;
#pragma unroll
        for (int ni = 0; ni < 4; ++ni)
            op[ni * 16 + cl] = (bf16_t)(o[ni][r4] * inv);
    }
}

// ---------------------------------------------------------------------------
extern "C" void kernel_launch(void* const* d_in, const int* in_sizes, int n_in,
                              void* d_out, int out_size, void* d_ws, size_t ws_size,
                              hipStream_t stream) {
    const void* x = d_in[0];
    const void* gamma = d_in[1];
    const void* beta = d_in[2];
    const void* Wq = d_in[3];
    const void* Wkv = d_in[4];
    const void* Wo = d_in[5];

    char* wsb = (char*)d_ws;
    int* flag = (int*)wsb;
    bf16_t* xn = (bf16_t*)(wsb + 256);            // 8192*768
    bf16_t* WqkvT = xn + (size_t)8192 * 768;      // 1536*768
    bf16_t* WoT = WqkvT + (size_t)1536 * 768;     // 768*512
    bf16_t* qkv = WoT + (size_t)768 * 512;        // 8192*1536 (V region unused)
    bf16_t* aob = xn;                             // alias: xn dead after QKV gemm
    bf16_t* vtg = (bf16_t*)d_out;                 // scratch until final GEMM

    // 1: LN + weight transposes + dtype flag
    prep_kernel<<<2432, 256, 0, stream>>>(x, gamma, beta, Wq, Wkv, Wo, xn, WqkvT, WoT,
                                          flag);

    // 2: fused QKV projection (Q pre-scaled; V written transposed to vtg)
    qkv_gemm<<<dim3(12, 64), 256, 0, stream>>>(xn, WqkvT, qkv, vtg, 8192, 1536, 768);

    // 3: attention (64-row blocks, 4 blocks/CU)
    attn_kernel<<<dim3(64, 16), 256, 0, stream>>>(qkv, vtg, aob);

    // 4: output projection
    gemm_bt64<<<dim3(12, 64), 128, 0, stream>>>(aob, WoT, d_out, 8192, 768, 512, flag);
}

// Round 6
// 234.089 us; speedup vs baseline: 1.0953x; 1.0953x over previous
//
#include <hip/hip_runtime.h>
#include <hip/hip_bf16.h>

// x(2,4096,768) -> LN -> QKV proj -> 8-head attention (d=64) -> Wo.
// Inputs fp32 (runtime-detected); internal pipeline bf16.
// B=2, L=4096, DIM=768, HEADS=8, DHEAD=64, INNER=512.
// 4 dispatches: prep (LN + W^T + flag), QKV GEMM (Q pre-scaled, V written
// transposed straight to vtg), attention (v12 = v10 compute with per-rt
// 16-row P bands (Ps 34.8->8.7 KB) freeing LDS for DOUBLE-BUFFERED K/V ->
// ONE barrier per 64-token iter instead of two; same 72-MFMA16 phases,
// same split-K, combine scratch in dead Ks region), output GEMM.

typedef __bf16 bf16_t;
typedef __bf16 bf16x4 __attribute__((ext_vector_type(4)));
typedef __bf16 bf16x8 __attribute__((ext_vector_type(8)));
typedef float f32x4 __attribute__((ext_vector_type(4)));
typedef unsigned int u32x2 __attribute__((ext_vector_type(2)));

#define MFMA16(a, b, c) __builtin_amdgcn_mfma_f32_16x16x32_bf16((a), (b), (c), 0, 0, 0)

// 0.125 (softmax scale^2) * log2(e): scores come out of QK^T in log2 units.
#define QSCALE 0.18033688011112042f

// async global->LDS, 16 B per lane; LDS dst = wave-uniform base + lane*16.
#define GLDS(gp, lp)                                                          \
    __builtin_amdgcn_global_load_lds(                                         \
        (const __attribute__((address_space(1))) void*)(gp),                  \
        (__attribute__((address_space(3))) void*)(lp), 16, 0, 0)

// ---------------------------------------------------------------------------
// Per-wave input-dtype detect: 1 = fp32, 0 = bf16. 128 L2-hot words.
// ---------------------------------------------------------------------------
__device__ __forceinline__ int detect_f32(const unsigned int* __restrict__ xw) {
    const int l = threadIdx.x & 63;
    int cnt = 0;
#pragma unroll
    for (int j = 0; j < 2; ++j) {
        const unsigned int e = (xw[l * 2 + j] >> 7) & 0xFF;
        cnt += (e >= 100 && e <= 140) ? 1 : 0;
    }
#pragma unroll
    for (int off = 1; off < 64; off <<= 1) cnt += __shfl_xor(cnt, off, 64);
    return cnt < 64;
}

// ---------------------------------------------------------------------------
// prep: blocks 0..2047 = LayerNorm (4 rows each, wave-per-row);
// blocks 2048..2431 = 64x64 transpose tiles of Wq/Wkv/Wo -> bf16 W^T.
// ---------------------------------------------------------------------------
__global__ __launch_bounds__(256) void prep_kernel(
    const void* __restrict__ xv, const void* __restrict__ gv,
    const void* __restrict__ bv, const void* __restrict__ wq,
    const void* __restrict__ wkv, const void* __restrict__ wo,
    bf16_t* __restrict__ xn, bf16_t* __restrict__ WqkvT, bf16_t* __restrict__ WoT,
    int* __restrict__ flag) {
    const int f32 = detect_f32((const unsigned int*)xv);
    const int bid = blockIdx.x;
    const int t = threadIdx.x;
    if (bid == 0 && t == 0) *flag = f32;

    __shared__ bf16_t Ts[64 * 68];

    if (bid < 2048) {
        const int lane = t & 63;
        const int row = bid * 4 + (t >> 6);
        const int c0 = lane * 12;
        float v[12];
        if (f32) {
            const float* xr = (const float*)xv + (size_t)row * 768 + c0;
#pragma unroll
            for (int i = 0; i < 3; ++i) {
                const float4 q = *(const float4*)(xr + i * 4);
                v[i * 4] = q.x; v[i * 4 + 1] = q.y;
                v[i * 4 + 2] = q.z; v[i * 4 + 3] = q.w;
            }
        } else {
            const bf16_t* xr = (const bf16_t*)xv + (size_t)row * 768 + c0;
#pragma unroll
            for (int i = 0; i < 3; ++i) {
                const bf16x4 q = *(const bf16x4*)(xr + i * 4);
#pragma unroll
                for (int j = 0; j < 4; ++j) v[i * 4 + j] = (float)q[j];
            }
        }
        float s = 0.f, sq = 0.f;
#pragma unroll
        for (int j = 0; j < 12; ++j) { s += v[j]; sq += v[j] * v[j]; }
#pragma unroll
        for (int off = 1; off < 64; off <<= 1) {
            s += __shfl_xor(s, off, 64);
            sq += __shfl_xor(sq, off, 64);
        }
        const float mu = s * (1.0f / 768.0f);
        const float var = sq * (1.0f / 768.0f) - mu * mu;
        const float rstd = rsqrtf(var + 1e-5f);

        bf16_t* xo = xn + (size_t)row * 768 + c0;
#pragma unroll
        for (int i = 0; i < 3; ++i) {
            bf16x4 o;
#pragma unroll
            for (int j = 0; j < 4; ++j) {
                const int c = c0 + i * 4 + j;
                const float gc = f32 ? ((const float*)gv)[c] : (float)((const bf16_t*)gv)[c];
                const float bc = f32 ? ((const float*)bv)[c] : (float)((const bf16_t*)bv)[c];
                o[j] = (bf16_t)((v[i * 4 + j] - mu) * rstd * gc + bc);
            }
            *(bf16x4*)(xo + i * 4) = o;
        }
        return;
    }

    int idx = bid - 2048;
    const void* in;
    bf16_t* out;
    int R, C, cx, ry;
    if (idx < 96) {                       // Wq: 768x512 -> WqkvT[0..511][768]
        in = wq; out = WqkvT; R = 768; C = 512;
        cx = idx & 7; ry = idx >> 3;
    } else if (idx < 288) {               // Wkv: 768x1024 -> WqkvT[512..1535][768]
        idx -= 96;
        in = wkv; out = WqkvT + (size_t)512 * 768; R = 768; C = 1024;
        cx = idx & 15; ry = idx >> 4;
    } else {                              // Wo: 512x768 -> WoT[768][512]
        idx -= 288;
        in = wo; out = WoT; R = 512; C = 768;
        cx = idx % 12; ry = idx / 12;
    }
    const int r0 = ry * 64, c0 = cx * 64;
    {
        const int r = t >> 2, c = (t & 3) * 16;
        if (f32) {
            const float* src = (const float*)in + (size_t)(r0 + r) * C + c0 + c;
#pragma unroll
            for (int i = 0; i < 16; i += 4) {
                const float4 q = *(const float4*)(src + i);
                Ts[r * 68 + c + i] = (bf16_t)q.x;
                Ts[r * 68 + c + i + 1] = (bf16_t)q.y;
                Ts[r * 68 + c + i + 2] = (bf16_t)q.z;
                Ts[r * 68 + c + i + 3] = (bf16_t)q.w;
            }
        } else {
            const bf16_t* src = (const bf16_t*)in + (size_t)(r0 + r) * C + c0 + c;
            *(bf16x8*)&Ts[r * 68 + c] = *(const bf16x8*)src;
            *(bf16x8*)&Ts[r * 68 + c + 8] = *(const bf16x8*)(src + 8);
        }
    }
    __syncthreads();
    {
        const int oc = t >> 2, seg = (t & 3) * 16;
        bf16x8 v0, v1;
#pragma unroll
        for (int j = 0; j < 8; ++j) v0[j] = Ts[(seg + j) * 68 + oc];
#pragma unroll
        for (int j = 0; j < 8; ++j) v1[j] = Ts[(seg + 8 + j) * 68 + oc];
        bf16_t* dst = out + (size_t)(c0 + oc) * R + r0 + seg;
        *(bf16x8*)dst = v0;
        *(bf16x8*)(dst + 8) = v1;
    }
}

// ---------------------------------------------------------------------------
// QKV GEMM (m97-style): qkv[M][1536] = xn @ WqkvT^T. 128x128 tile, BK=32,
// global_load_lds width 16. Epilogue: Q cols (<512) scaled by QSCALE; K cols
// written to qkv; V cols (>=1024) written TRANSPOSED to vtg[bh][d][tok].
// ---------------------------------------------------------------------------
__global__ __launch_bounds__(256) void qkv_gemm(const bf16_t* __restrict__ A,
                                                const bf16_t* __restrict__ BT,
                                                bf16_t* __restrict__ qkv,
                                                bf16_t* __restrict__ vtg,
                                                int M, int N, int K) {
    const int m0 = blockIdx.y * 128;
    const int n0 = blockIdx.x * 128;
    __shared__ bf16_t As[128 * 32];
    __shared__ bf16_t Bs[128 * 32];

    const int t = threadIdx.x;
    const int lane = t & 63;
    const int w = t >> 6;
    const int wm = (w >> 1) * 64;
    const int wn = (w & 1) * 64;
    const int quad = lane >> 4;
    const int cl = lane & 15;

    f32x4 acc[4][4];
    const f32x4 z4 = {0.f, 0.f, 0.f, 0.f};
#pragma unroll
    for (int mi = 0; mi < 4; ++mi)
#pragma unroll
        for (int ni = 0; ni < 4; ++ni) acc[mi][ni] = z4;

    const int r0 = lane >> 2;
    const int c0 = (lane & 3) * 8;
    const bf16_t* AgL = A + (size_t)(m0 + w * 32 + r0) * K + c0;
    const bf16_t* AgH = A + (size_t)(m0 + w * 32 + 16 + r0) * K + c0;
    const bf16_t* BgL = BT + (size_t)(n0 + w * 32 + r0) * K + c0;
    const bf16_t* BgH = BT + (size_t)(n0 + w * 32 + 16 + r0) * K + c0;
    bf16_t* AdL = &As[(w * 32) * 32];
    bf16_t* AdH = &As[(w * 32 + 16) * 32];
    bf16_t* BdL = &Bs[(w * 32) * 32];
    bf16_t* BdH = &Bs[(w * 32 + 16) * 32];

    for (int kt = 0; kt < K; kt += 32) {
        __syncthreads();
        GLDS(AgL + kt, AdL);
        GLDS(AgH + kt, AdH);
        GLDS(BgL + kt, BdL);
        GLDS(BgH + kt, BdH);
        __syncthreads();  // drains vmcnt(0): LDS tiles complete

        const int ko = quad * 8;
        bf16x8 af[4], bfr[4];
#pragma unroll
        for (int mi = 0; mi < 4; ++mi)
            af[mi] = *(const bf16x8*)&As[(wm + mi * 16 + cl) * 32 + ko];
#pragma unroll
        for (int ni = 0; ni < 4; ++ni)
            bfr[ni] = *(const bf16x8*)&Bs[(wn + ni * 16 + cl) * 32 + ko];
#pragma unroll
        for (int mi = 0; mi < 4; ++mi)
#pragma unroll
            for (int ni = 0; ni < 4; ++ni)
                acc[mi][ni] = MFMA16(af[mi], bfr[ni], acc[mi][ni]);
    }

    if (n0 >= 1024) {
        // ---- V tile: write transposed to vtg[(b*8+h)*64+d][tok] ----
        const int b = m0 >> 12;
#pragma unroll
        for (int mi = 0; mi < 4; ++mi) {
#pragma unroll
            for (int ni = 0; ni < 4; ++ni) {
                const int tok = (m0 & 4095) + wm + mi * 16 + quad * 4;
                const int dl = n0 + wn + ni * 16 + cl - 1024;   // 0..511
                bf16x4 pk;
#pragma unroll
                for (int r4 = 0; r4 < 4; ++r4) pk[r4] = (bf16_t)acc[mi][ni][r4];
                *(bf16x4*)(vtg + ((size_t)(b * 8 + (dl >> 6)) * 64 + (dl & 63)) * 4096 +
                           tok) = pk;
            }
        }
    } else {
        const float sc = (n0 < 512) ? QSCALE : 1.0f;
#pragma unroll
        for (int mi = 0; mi < 4; ++mi) {
#pragma unroll
            for (int ni = 0; ni < 4; ++ni) {
#pragma unroll
                for (int r4 = 0; r4 < 4; ++r4) {
                    const int row = m0 + wm + mi * 16 + quad * 4 + r4;
                    const int col = n0 + wn + ni * 16 + cl;
                    qkv[(size_t)row * N + col] = (bf16_t)(acc[mi][ni][r4] * sc);
                }
            }
        }
    }
}

// ---------------------------------------------------------------------------
// GEMM, 128(M)x64(N) 2-wave blocks for the final projection. Output fp32 or
// bf16 per *out_flag.
// ---------------------------------------------------------------------------
__global__ __launch_bounds__(128) void gemm_bt64(const bf16_t* __restrict__ A,
                                                 const bf16_t* __restrict__ BT,
                                                 void* __restrict__ C,
                                                 int M, int N, int K,
                                                 const int* __restrict__ out_flag) {
    const int m0 = blockIdx.y * 128;
    const int n0 = blockIdx.x * 64;
    __shared__ bf16_t As[128 * 32];
    __shared__ bf16_t Bs[64 * 32];

    const int t = threadIdx.x;
    const int lane = t & 63;
    const int w = t >> 6;  // 0..1
    const int quad = lane >> 4;
    const int cl = lane & 15;

    f32x4 acc[4][4];
    const f32x4 z4 = {0.f, 0.f, 0.f, 0.f};
#pragma unroll
    for (int mi = 0; mi < 4; ++mi)
#pragma unroll
        for (int ni = 0; ni < 4; ++ni) acc[mi][ni] = z4;

    const int r0 = lane >> 2;
    const int c0 = (lane & 3) * 8;
    const bf16_t* Ag = A + (size_t)(m0 + w * 64 + r0) * K + c0;
    const bf16_t* Bg = BT + (size_t)(n0 + w * 32 + r0) * K + c0;
    bf16_t* Ad = &As[(w * 64) * 32];
    bf16_t* Bd = &Bs[(w * 32) * 32];

    for (int kt = 0; kt < K; kt += 32) {
        __syncthreads();
#pragma unroll
        for (int i = 0; i < 4; ++i) GLDS(Ag + kt + (size_t)i * 16 * K, Ad + i * 512);
#pragma unroll
        for (int i = 0; i < 2; ++i) GLDS(Bg + kt + (size_t)i * 16 * K, Bd + i * 512);
        __syncthreads();

        const int ko = quad * 8;
        bf16x8 af[4], bfr[4];
#pragma unroll
        for (int mi = 0; mi < 4; ++mi)
            af[mi] = *(const bf16x8*)&As[(w * 64 + mi * 16 + cl) * 32 + ko];
#pragma unroll
        for (int ni = 0; ni < 4; ++ni)
            bfr[ni] = *(const bf16x8*)&Bs[(ni * 16 + cl) * 32 + ko];
#pragma unroll
        for (int mi = 0; mi < 4; ++mi)
#pragma unroll
            for (int ni = 0; ni < 4; ++ni)
                acc[mi][ni] = MFMA16(af[mi], bfr[ni], acc[mi][ni]);
    }

    const int f32out = *out_flag;
#pragma unroll
    for (int mi = 0; mi < 4; ++mi) {
#pragma unroll
        for (int ni = 0; ni < 4; ++ni) {
#pragma unroll
            for (int r4 = 0; r4 < 4; ++r4) {
                const int row = m0 + w * 64 + mi * 16 + quad * 4 + r4;
                const int col = n0 + ni * 16 + cl;
                if (f32out)
                    ((float*)C)[(size_t)row * N + col] = acc[mi][ni][r4];
                else
                    ((bf16_t*)C)[(size_t)row * N + col] = (bf16_t)acc[mi][ni][r4];
            }
        }
    }
}

// ---------------------------------------------------------------------------
// Flash attention v12: v10 phases (72 MFMA16/wave-iter) with double-buffered
// K/V and ONE barrier per iter. Ps shrunk to per-wave 16-row bands (written
// and consumed per rt sub-block inside the same wave -> no extra sync).
// Pipeline: iter i stores tile i+1 into buf[(i+1)&1] (regs prefetched in
// iter i-1), issues loads for tile i+2, computes tile i from buf[i&1], then
// ONE barrier. Epilogue split-K combine uses the dead Ks region as scratch.
// ---------------------------------------------------------------------------
__global__ __launch_bounds__(256, 2) void attn_kernel(const bf16_t* __restrict__ qkv,
                                                      const bf16_t* __restrict__ vtg,
                                                      bf16_t* __restrict__ ao) {
    const int qt = blockIdx.x;    // 0..31  (128-row q tile)
    const int bh = blockIdx.y;    // 0..15
    const int b = bh >> 3, h = bh & 7;
    const int q0 = qt * 128;

    __shared__ bf16_t Ps[4][16 * 68];     // per-wave 16-row P band (8.7 KB)
    __shared__ bf16_t Ks[2][2][64 * 68];  // [buf][kh][tok][d]; buf0 = Q staging
    __shared__ bf16_t Vs[2][2][64 * 68];  // [buf][kh][d][tok]

    const int t = threadIdx.x;
    const int lane = t & 63;
    const int w = t >> 6;
    const int qsub = w & 1;
    const int kh = w >> 1;
    const int quad = lane >> 4;
    const int cl = lane & 15;

    const size_t rowbase = (size_t)b * 4096;
    const int qcol = h * 64;
    const int kcol = 512 + h * 64;

    // ---- stage Q (128x64, pre-scaled) via GLDS into Ks[0] area ----
    bf16_t* Qtr = &Ks[0][0][0];
    {
        const bf16_t* qsrc = qkv + (rowbase + q0 + w * 32) * 1536 + qcol;
#pragma unroll
        for (int i = 0; i < 4; ++i)
            GLDS(qsrc + (size_t)(i * 8 + (lane >> 3)) * 1536 + (lane & 7) * 8,
                 Qtr + (w * 32 + i * 8) * 64);
    }

    // ---- staging ids (per kh wave-pair: 128 threads cover 64 rows x 2 halves)
    const int t2 = qsub * 64 + lane;
    const int sr = t2 >> 1;
    const int sh = (t2 & 1) * 32;
    const bf16_t* kgp = qkv + (rowbase + kh * 2048 + sr) * 1536 + kcol + sh;
    const bf16_t* vgp = vtg + ((size_t)bh * 64 + sr) * 4096 + kh * 2048 + sh;
    size_t koff = 0, voff = 0;
    bf16x8 kreg[4], vreg[4];

#define LOADT()                                                       \
    do {                                                              \
        _Pragma("unroll")                                             \
        for (int o8 = 0; o8 < 4; ++o8) {                              \
            kreg[o8] = *(const bf16x8*)(kgp + koff + o8 * 8);         \
            vreg[o8] = *(const bf16x8*)(vgp + voff + o8 * 8);         \
        }                                                             \
        koff += (size_t)64 * 1536;                                    \
        voff += 64;                                                   \
    } while (0)
#define STORET(bq)                                                    \
    do {                                                              \
        _Pragma("unroll")                                             \
        for (int o8 = 0; o8 < 4; ++o8) {                              \
            *(bf16x8*)&Ks[bq][kh][sr * 68 + sh + o8 * 8] = kreg[o8];  \
            *(bf16x8*)&Vs[bq][kh][sr * 68 + sh + o8 * 8] = vreg[o8];  \
        }                                                             \
    } while (0)

    LOADT();                 // tile 0 -> regs (in flight with Q GLDS)
    __syncthreads();         // Q staged + tile0 regs ready (vmcnt drained)

    bf16x8 aq[4][2];
#pragma unroll
    for (int rt = 0; rt < 4; ++rt)
#pragma unroll
        for (int hh = 0; hh < 2; ++hh)
            aq[rt][hh] =
                *(const bf16x8*)&Qtr[(qsub * 64 + rt * 16 + cl) * 64 + hh * 32 + quad * 8];

    __syncthreads();         // all aq reads done; Ks[0] reusable
    STORET(0);               // tile 0 -> buf0
    LOADT();                 // tile 1 -> regs
    __syncthreads();         // buf0 visible to all waves

    bf16x8 ones;
#pragma unroll
    for (int e = 0; e < 8; ++e) ones[e] = (bf16_t)1.0f;

    const f32x4 z4 = {0.f, 0.f, 0.f, 0.f};
    f32x4 o[4][4];
    f32x4 l_acc[4];
#pragma unroll
    for (int rt = 0; rt < 4; ++rt) {
        l_acc[rt] = z4;
#pragma unroll
        for (int ni = 0; ni < 4; ++ni) o[rt][ni] = z4;
    }

    const int ko = quad * 8;

#define COMPUTE(bq)                                                              \
    do {                                                                         \
        bf16x8 kb[4][2], vb[4][2];                                               \
        _Pragma("unroll")                                                        \
        for (int ni = 0; ni < 4; ++ni) {                                         \
            kb[ni][0] = *(const bf16x8*)&Ks[bq][kh][(ni * 16 + cl) * 68 + ko];   \
            kb[ni][1] = *(const bf16x8*)&Ks[bq][kh][(ni * 16 + cl) * 68 + 32 + ko]; \
            vb[ni][0] = *(const bf16x8*)&Vs[bq][kh][(ni * 16 + cl) * 68 + ko];   \
            vb[ni][1] = *(const bf16x8*)&Vs[bq][kh][(ni * 16 + cl) * 68 + 32 + ko]; \
        }                                                                        \
        __builtin_amdgcn_s_setprio(1);                                           \
        _Pragma("unroll")                                                        \
        for (int rt = 0; rt < 4; ++rt) {                                         \
            _Pragma("unroll")                                                    \
            for (int ni = 0; ni < 4; ++ni) {                                     \
                f32x4 s = z4;                                                    \
                s = MFMA16(kb[ni][0], aq[rt][0], s);                             \
                s = MFMA16(kb[ni][1], aq[rt][1], s);                             \
                const float e0 = __builtin_amdgcn_exp2f(s[0]);                   \
                const float e1 = __builtin_amdgcn_exp2f(s[1]);                   \
                const float e2 = __builtin_amdgcn_exp2f(s[2]);                   \
                const float e3 = __builtin_amdgcn_exp2f(s[3]);                   \
                u32x2 pk;                                                        \
                asm("v_cvt_pk_bf16_f32 %0, %1, %2" : "=v"(pk[0]) : "v"(e0), "v"(e1)); \
                asm("v_cvt_pk_bf16_f32 %0, %1, %2" : "=v"(pk[1]) : "v"(e2), "v"(e3)); \
                *(u32x2*)&Ps[w][cl * 68 + ni * 16 + quad * 4] = pk;              \
            }                                                                    \
            const bf16x8 p0 = *(const bf16x8*)&Ps[w][cl * 68 + ko];              \
            const bf16x8 p1 = *(const bf16x8*)&Ps[w][cl * 68 + 32 + ko];         \
            _Pragma("unroll")                                                    \
            for (int ni = 0; ni < 4; ++ni) {                                     \
                o[rt][ni] = MFMA16(p0, vb[ni][0], o[rt][ni]);                    \
                o[rt][ni] = MFMA16(p1, vb[ni][1], o[rt][ni]);                    \
            }                                                                    \
            l_acc[rt] = MFMA16(p0, ones, l_acc[rt]);                             \
            l_acc[rt] = MFMA16(p1, ones, l_acc[rt]);                             \
        }                                                                        \
        __builtin_amdgcn_s_setprio(0);                                           \
    } while (0)

    for (int it2 = 0; it2 < 16; ++it2) {
        // ---- body A: compute tile 2*it2 from buf0 ----
        STORET(1);                     // tile 2*it2+1 (regs from prev iter)
        if (it2 < 15) LOADT();         // tile 2*it2+2 -> regs
        COMPUTE(0);
        __syncthreads();

        // ---- body B: compute tile 2*it2+1 from buf1 ----
        if (it2 < 15) {
            STORET(0);                 // tile 2*it2+2
            LOADT();                   // tile 2*it2+3 -> regs
        }
        COMPUTE(1);
        __syncthreads();
    }
#undef LOADT
#undef STORET
#undef COMPUTE

    // ---- split-K combine via LDS scratch in dead Ks region ----
    float* cb = (float*)&Ks[0][0][0];  // 2 regions of 64x65 fp32 (col 64 = l)
    if (kh == 1) {
#pragma unroll
        for (int rt = 0; rt < 4; ++rt) {
#pragma unroll
            for (int r4 = 0; r4 < 4; ++r4) {
                const int row = rt * 16 + quad * 4 + r4;
                float* rp = cb + qsub * 4160 + row * 65;
#pragma unroll
                for (int ni = 0; ni < 4; ++ni) rp[ni * 16 + cl] = o[rt][ni][r4];
                if (cl == 0) rp[64] = l_acc[rt][r4];
            }
        }
    }
    __syncthreads();
    if (kh == 0) {
#pragma unroll
        for (int rt = 0; rt < 4; ++rt) {
#pragma unroll
            for (int r4 = 0; r4 < 4; ++r4) {
                const int row = rt * 16 + quad * 4 + r4;
                const float* rp = cb + qsub * 4160 + row * 65;
                const float inv = 1.0f / (l_acc[rt][r4] + rp[64]);
                const size_t orow = rowbase + q0 + qsub * 64 + row;
#pragma unroll
                for (int ni = 0; ni < 4; ++ni)
                    ao[orow * 512 + h * 64 + ni * 16 + cl] =
                        (bf16_t)((o[rt][ni][r4] + rp[ni * 16 + cl]) * inv);
            }
        }
    }
}

// ---------------------------------------------------------------------------
extern "C" void kernel_launch(void* const* d_in, const int* in_sizes, int n_in,
                              void* d_out, int out_size, void* d_ws, size_t ws_size,
                              hipStream_t stream) {
    const void* x = d_in[0];
    const void* gamma = d_in[1];
    const void* beta = d_in[2];
    const void* Wq = d_in[3];
    const void* Wkv = d_in[4];
    const void* Wo = d_in[5];

    char* wsb = (char*)d_ws;
    int* flag = (int*)wsb;
    bf16_t* xn = (bf16_t*)(wsb + 256);            // 8192*768
    bf16_t* WqkvT = xn + (size_t)8192 * 768;      // 1536*768
    bf16_t* WoT = WqkvT + (size_t)1536 * 768;     // 768*512
    bf16_t* qkv = WoT + (size_t)768 * 512;        // 8192*1536 (V region unused)
    bf16_t* aob = xn;                             // alias: xn dead after QKV gemm
    bf16_t* vtg = (bf16_t*)d_out;                 // scratch until final GEMM

    // 1: LN + weight transposes + dtype flag
    prep_kernel<<<2432, 256, 0, stream>>>(x, gamma, beta, Wq, Wkv, Wo, xn, WqkvT, WoT,
                                          flag);

    // 2: fused QKV projection (Q pre-scaled; V written transposed to vtg)
    qkv_gemm<<<dim3(12, 64), 256, 0, stream>>>(xn, WqkvT, qkv, vtg, 8192, 1536, 768);

    // 3: attention (double-buffered K/V, one barrier per 64-token tile)
    attn_kernel<<<dim3(32, 16), 256, 0, stream>>>(qkv, vtg, aob);

    // 4: output projection
    gemm_bt64<<<dim3(12, 64), 128, 0, stream>>>(aob, WoT, d_out, 8192, 768, 512, flag);
}

// Round 7
// 228.630 us; speedup vs baseline: 1.1215x; 1.0239x over previous
//
#include <hip/hip_runtime.h>
#include <hip/hip_bf16.h>

// x(2,4096,768) -> LN -> QKV proj -> 8-head attention (d=64) -> Wo.
// Inputs fp32 (runtime-detected); internal pipeline bf16.
// B=2, L=4096, DIM=768, HEADS=8, DHEAD=64, INNER=512.
// 4 dispatches: prep (LN + W^T + flag), QKV GEMM (Q pre-scaled, V written
// transposed straight to vtg), attention (v13 = v12's staging pipeline
// [reg-prefetch 1 phase ahead, dbuf K/V, 1 barrier/tile] + v8's compute core
// [MFMA32 swapped QK^T, in-register P via cvt_pk_bf16+permlane32_swap, l via
// mfma(P,ones), direct epilogue]; no P LDS, no split-K), output GEMM.

typedef __bf16 bf16_t;
typedef __bf16 bf16x4 __attribute__((ext_vector_type(4)));
typedef __bf16 bf16x8 __attribute__((ext_vector_type(8)));
typedef float f32x4 __attribute__((ext_vector_type(4)));
typedef float f32x16 __attribute__((ext_vector_type(16)));
typedef unsigned int u32x2 __attribute__((ext_vector_type(2)));
typedef unsigned int u32x4 __attribute__((ext_vector_type(4)));

#define MFMA16(a, b, c) __builtin_amdgcn_mfma_f32_16x16x32_bf16((a), (b), (c), 0, 0, 0)
#define MFMA32(a, b, c) __builtin_amdgcn_mfma_f32_32x32x16_bf16((a), (b), (c), 0, 0, 0)

// 0.125 (softmax scale^2) * log2(e): scores come out of QK^T in log2 units.
#define QSCALE 0.18033688011112042f

// async global->LDS, 16 B per lane; LDS dst = wave-uniform base + lane*16.
#define GLDS(gp, lp)                                                          \
    __builtin_amdgcn_global_load_lds(                                         \
        (const __attribute__((address_space(1))) void*)(gp),                  \
        (__attribute__((address_space(3))) void*)(lp), 16, 0, 0)

// ---------------------------------------------------------------------------
// Per-wave input-dtype detect: 1 = fp32, 0 = bf16. 128 L2-hot words.
// ---------------------------------------------------------------------------
__device__ __forceinline__ int detect_f32(const unsigned int* __restrict__ xw) {
    const int l = threadIdx.x & 63;
    int cnt = 0;
#pragma unroll
    for (int j = 0; j < 2; ++j) {
        const unsigned int e = (xw[l * 2 + j] >> 7) & 0xFF;
        cnt += (e >= 100 && e <= 140) ? 1 : 0;
    }
#pragma unroll
    for (int off = 1; off < 64; off <<= 1) cnt += __shfl_xor(cnt, off, 64);
    return cnt < 64;
}

// ---------------------------------------------------------------------------
// prep: blocks 0..2047 = LayerNorm (4 rows each, wave-per-row);
// blocks 2048..2431 = 64x64 transpose tiles of Wq/Wkv/Wo -> bf16 W^T.
// ---------------------------------------------------------------------------
__global__ __launch_bounds__(256) void prep_kernel(
    const void* __restrict__ xv, const void* __restrict__ gv,
    const void* __restrict__ bv, const void* __restrict__ wq,
    const void* __restrict__ wkv, const void* __restrict__ wo,
    bf16_t* __restrict__ xn, bf16_t* __restrict__ WqkvT, bf16_t* __restrict__ WoT,
    int* __restrict__ flag) {
    const int f32 = detect_f32((const unsigned int*)xv);
    const int bid = blockIdx.x;
    const int t = threadIdx.x;
    if (bid == 0 && t == 0) *flag = f32;

    __shared__ bf16_t Ts[64 * 68];

    if (bid < 2048) {
        const int lane = t & 63;
        const int row = bid * 4 + (t >> 6);
        const int c0 = lane * 12;
        float v[12];
        if (f32) {
            const float* xr = (const float*)xv + (size_t)row * 768 + c0;
#pragma unroll
            for (int i = 0; i < 3; ++i) {
                const float4 q = *(const float4*)(xr + i * 4);
                v[i * 4] = q.x; v[i * 4 + 1] = q.y;
                v[i * 4 + 2] = q.z; v[i * 4 + 3] = q.w;
            }
        } else {
            const bf16_t* xr = (const bf16_t*)xv + (size_t)row * 768 + c0;
#pragma unroll
            for (int i = 0; i < 3; ++i) {
                const bf16x4 q = *(const bf16x4*)(xr + i * 4);
#pragma unroll
                for (int j = 0; j < 4; ++j) v[i * 4 + j] = (float)q[j];
            }
        }
        float s = 0.f, sq = 0.f;
#pragma unroll
        for (int j = 0; j < 12; ++j) { s += v[j]; sq += v[j] * v[j]; }
#pragma unroll
        for (int off = 1; off < 64; off <<= 1) {
            s += __shfl_xor(s, off, 64);
            sq += __shfl_xor(sq, off, 64);
        }
        const float mu = s * (1.0f / 768.0f);
        const float var = sq * (1.0f / 768.0f) - mu * mu;
        const float rstd = rsqrtf(var + 1e-5f);

        bf16_t* xo = xn + (size_t)row * 768 + c0;
#pragma unroll
        for (int i = 0; i < 3; ++i) {
            bf16x4 o;
#pragma unroll
            for (int j = 0; j < 4; ++j) {
                const int c = c0 + i * 4 + j;
                const float gc = f32 ? ((const float*)gv)[c] : (float)((const bf16_t*)gv)[c];
                const float bc = f32 ? ((const float*)bv)[c] : (float)((const bf16_t*)bv)[c];
                o[j] = (bf16_t)((v[i * 4 + j] - mu) * rstd * gc + bc);
            }
            *(bf16x4*)(xo + i * 4) = o;
        }
        return;
    }

    int idx = bid - 2048;
    const void* in;
    bf16_t* out;
    int R, C, cx, ry;
    if (idx < 96) {                       // Wq: 768x512 -> WqkvT[0..511][768]
        in = wq; out = WqkvT; R = 768; C = 512;
        cx = idx & 7; ry = idx >> 3;
    } else if (idx < 288) {               // Wkv: 768x1024 -> WqkvT[512..1535][768]
        idx -= 96;
        in = wkv; out = WqkvT + (size_t)512 * 768; R = 768; C = 1024;
        cx = idx & 15; ry = idx >> 4;
    } else {                              // Wo: 512x768 -> WoT[768][512]
        idx -= 288;
        in = wo; out = WoT; R = 512; C = 768;
        cx = idx % 12; ry = idx / 12;
    }
    const int r0 = ry * 64, c0 = cx * 64;
    {
        const int r = t >> 2, c = (t & 3) * 16;
        if (f32) {
            const float* src = (const float*)in + (size_t)(r0 + r) * C + c0 + c;
#pragma unroll
            for (int i = 0; i < 16; i += 4) {
                const float4 q = *(const float4*)(src + i);
                Ts[r * 68 + c + i] = (bf16_t)q.x;
                Ts[r * 68 + c + i + 1] = (bf16_t)q.y;
                Ts[r * 68 + c + i + 2] = (bf16_t)q.z;
                Ts[r * 68 + c + i + 3] = (bf16_t)q.w;
            }
        } else {
            const bf16_t* src = (const bf16_t*)in + (size_t)(r0 + r) * C + c0 + c;
            *(bf16x8*)&Ts[r * 68 + c] = *(const bf16x8*)src;
            *(bf16x8*)&Ts[r * 68 + c + 8] = *(const bf16x8*)(src + 8);
        }
    }
    __syncthreads();
    {
        const int oc = t >> 2, seg = (t & 3) * 16;
        bf16x8 v0, v1;
#pragma unroll
        for (int j = 0; j < 8; ++j) v0[j] = Ts[(seg + j) * 68 + oc];
#pragma unroll
        for (int j = 0; j < 8; ++j) v1[j] = Ts[(seg + 8 + j) * 68 + oc];
        bf16_t* dst = out + (size_t)(c0 + oc) * R + r0 + seg;
        *(bf16x8*)dst = v0;
        *(bf16x8*)(dst + 8) = v1;
    }
}

// ---------------------------------------------------------------------------
// QKV GEMM (m97-style): qkv[M][1536] = xn @ WqkvT^T. 128x128 tile, BK=32,
// global_load_lds width 16. Epilogue: Q cols (<512) scaled by QSCALE; K cols
// written to qkv; V cols (>=1024) written TRANSPOSED to vtg[bh][d][tok].
// ---------------------------------------------------------------------------
__global__ __launch_bounds__(256) void qkv_gemm(const bf16_t* __restrict__ A,
                                                const bf16_t* __restrict__ BT,
                                                bf16_t* __restrict__ qkv,
                                                bf16_t* __restrict__ vtg,
                                                int M, int N, int K) {
    const int m0 = blockIdx.y * 128;
    const int n0 = blockIdx.x * 128;
    __shared__ bf16_t As[128 * 32];
    __shared__ bf16_t Bs[128 * 32];

    const int t = threadIdx.x;
    const int lane = t & 63;
    const int w = t >> 6;
    const int wm = (w >> 1) * 64;
    const int wn = (w & 1) * 64;
    const int quad = lane >> 4;
    const int cl = lane & 15;

    f32x4 acc[4][4];
    const f32x4 z4 = {0.f, 0.f, 0.f, 0.f};
#pragma unroll
    for (int mi = 0; mi < 4; ++mi)
#pragma unroll
        for (int ni = 0; ni < 4; ++ni) acc[mi][ni] = z4;

    const int r0 = lane >> 2;
    const int c0 = (lane & 3) * 8;
    const bf16_t* AgL = A + (size_t)(m0 + w * 32 + r0) * K + c0;
    const bf16_t* AgH = A + (size_t)(m0 + w * 32 + 16 + r0) * K + c0;
    const bf16_t* BgL = BT + (size_t)(n0 + w * 32 + r0) * K + c0;
    const bf16_t* BgH = BT + (size_t)(n0 + w * 32 + 16 + r0) * K + c0;
    bf16_t* AdL = &As[(w * 32) * 32];
    bf16_t* AdH = &As[(w * 32 + 16) * 32];
    bf16_t* BdL = &Bs[(w * 32) * 32];
    bf16_t* BdH = &Bs[(w * 32 + 16) * 32];

    for (int kt = 0; kt < K; kt += 32) {
        __syncthreads();
        GLDS(AgL + kt, AdL);
        GLDS(AgH + kt, AdH);
        GLDS(BgL + kt, BdL);
        GLDS(BgH + kt, BdH);
        __syncthreads();  // drains vmcnt(0): LDS tiles complete

        const int ko = quad * 8;
        bf16x8 af[4], bfr[4];
#pragma unroll
        for (int mi = 0; mi < 4; ++mi)
            af[mi] = *(const bf16x8*)&As[(wm + mi * 16 + cl) * 32 + ko];
#pragma unroll
        for (int ni = 0; ni < 4; ++ni)
            bfr[ni] = *(const bf16x8*)&Bs[(wn + ni * 16 + cl) * 32 + ko];
#pragma unroll
        for (int mi = 0; mi < 4; ++mi)
#pragma unroll
            for (int ni = 0; ni < 4; ++ni)
                acc[mi][ni] = MFMA16(af[mi], bfr[ni], acc[mi][ni]);
    }

    if (n0 >= 1024) {
        // ---- V tile: write transposed to vtg[(b*8+h)*64+d][tok] ----
        const int b = m0 >> 12;
#pragma unroll
        for (int mi = 0; mi < 4; ++mi) {
#pragma unroll
            for (int ni = 0; ni < 4; ++ni) {
                const int tok = (m0 & 4095) + wm + mi * 16 + quad * 4;
                const int dl = n0 + wn + ni * 16 + cl - 1024;   // 0..511
                bf16x4 pk;
#pragma unroll
                for (int r4 = 0; r4 < 4; ++r4) pk[r4] = (bf16_t)acc[mi][ni][r4];
                *(bf16x4*)(vtg + ((size_t)(b * 8 + (dl >> 6)) * 64 + (dl & 63)) * 4096 +
                           tok) = pk;
            }
        }
    } else {
        const float sc = (n0 < 512) ? QSCALE : 1.0f;
#pragma unroll
        for (int mi = 0; mi < 4; ++mi) {
#pragma unroll
            for (int ni = 0; ni < 4; ++ni) {
#pragma unroll
                for (int r4 = 0; r4 < 4; ++r4) {
                    const int row = m0 + wm + mi * 16 + quad * 4 + r4;
                    const int col = n0 + wn + ni * 16 + cl;
                    qkv[(size_t)row * N + col] = (bf16_t)(acc[mi][ni][r4] * sc);
                }
            }
        }
    }
}

// ---------------------------------------------------------------------------
// GEMM, 128(M)x64(N) 2-wave blocks for the final projection. Output fp32 or
// bf16 per *out_flag.
// ---------------------------------------------------------------------------
__global__ __launch_bounds__(128) void gemm_bt64(const bf16_t* __restrict__ A,
                                                 const bf16_t* __restrict__ BT,
                                                 void* __restrict__ C,
                                                 int M, int N, int K,
                                                 const int* __restrict__ out_flag) {
    const int m0 = blockIdx.y * 128;
    const int n0 = blockIdx.x * 64;
    __shared__ bf16_t As[128 * 32];
    __shared__ bf16_t Bs[64 * 32];

    const int t = threadIdx.x;
    const int lane = t & 63;
    const int w = t >> 6;  // 0..1
    const int quad = lane >> 4;
    const int cl = lane & 15;

    f32x4 acc[4][4];
    const f32x4 z4 = {0.f, 0.f, 0.f, 0.f};
#pragma unroll
    for (int mi = 0; mi < 4; ++mi)
#pragma unroll
        for (int ni = 0; ni < 4; ++ni) acc[mi][ni] = z4;

    const int r0 = lane >> 2;
    const int c0 = (lane & 3) * 8;
    const bf16_t* Ag = A + (size_t)(m0 + w * 64 + r0) * K + c0;
    const bf16_t* Bg = BT + (size_t)(n0 + w * 32 + r0) * K + c0;
    bf16_t* Ad = &As[(w * 64) * 32];
    bf16_t* Bd = &Bs[(w * 32) * 32];

    for (int kt = 0; kt < K; kt += 32) {
        __syncthreads();
#pragma unroll
        for (int i = 0; i < 4; ++i) GLDS(Ag + kt + (size_t)i * 16 * K, Ad + i * 512);
#pragma unroll
        for (int i = 0; i < 2; ++i) GLDS(Bg + kt + (size_t)i * 16 * K, Bd + i * 512);
        __syncthreads();

        const int ko = quad * 8;
        bf16x8 af[4], bfr[4];
#pragma unroll
        for (int mi = 0; mi < 4; ++mi)
            af[mi] = *(const bf16x8*)&As[(w * 64 + mi * 16 + cl) * 32 + ko];
#pragma unroll
        for (int ni = 0; ni < 4; ++ni)
            bfr[ni] = *(const bf16x8*)&Bs[(ni * 16 + cl) * 32 + ko];
#pragma unroll
        for (int mi = 0; mi < 4; ++mi)
#pragma unroll
            for (int ni = 0; ni < 4; ++ni)
                acc[mi][ni] = MFMA16(af[mi], bfr[ni], acc[mi][ni]);
    }

    const int f32out = *out_flag;
#pragma unroll
    for (int mi = 0; mi < 4; ++mi) {
#pragma unroll
        for (int ni = 0; ni < 4; ++ni) {
#pragma unroll
            for (int r4 = 0; r4 < 4; ++r4) {
                const int row = m0 + w * 64 + mi * 16 + quad * 4 + r4;
                const int col = n0 + ni * 16 + cl;
                if (f32out)
                    ((float*)C)[(size_t)row * N + col] = acc[mi][ni][r4];
                else
                    ((bf16_t*)C)[(size_t)row * N + col] = (bf16_t)acc[mi][ni][r4];
            }
        }
    }
}

// ---------------------------------------------------------------------------
// Flash attention v13: 4 waves x 32 q-rows, full token range per block.
// K/V double-buffered in padded [64][68] LDS (69.6 KB, 2 blocks/CU), staged
// via regs with loads issued one full compute phase ahead (v12 pipeline),
// ONE barrier per tile. Compute core = v8's verified MFMA32 path: swapped
// QK^T (S^T = mfma32(K,Q)) so each lane owns P for its q-column; P -> PV
// A-frags in registers via v_cvt_pk_bf16_f32 + permlane32_swap (NO P LDS);
// l via mfma(P, ones) whose C-layout matches o's rows -> direct epilogue.
// ---------------------------------------------------------------------------
__global__ __launch_bounds__(256, 2) void attn_kernel(const bf16_t* __restrict__ qkv,
                                                      const bf16_t* __restrict__ vtg,
                                                      bf16_t* __restrict__ ao) {
    const int qt = blockIdx.x;    // 0..31  (128-row q tile)
    const int bh = blockIdx.y;    // 0..15
    const int b = bh >> 3, hd = bh & 7;
    const int q0 = qt * 128;

    __shared__ bf16_t Ks[2][64 * 68];   // [buf][tok][d], stride 68 (136 B)
    __shared__ bf16_t Vs[2][64 * 68];   // [buf][d][tok], stride 68

    const int t = threadIdx.x;
    const int lane = t & 63;
    const int w = t >> 6;         // 0..3: 32-row q subtile
    const int c = lane & 31;
    const int h = lane >> 5;

    const size_t rowbase = (size_t)b * 4096;
    const int qcol = hd * 64;
    const int kcol = 512 + hd * 64;
    const int q0w = q0 + w * 32;

    // ---- Q fragments (B-operand): lane holds Q[q0w+c][ks*16 + 8h .. +7] ----
    bf16x8 qf[4];
    {
        const bf16_t* qp = qkv + (rowbase + q0w + c) * 1536 + qcol + h * 8;
#pragma unroll
        for (int ks = 0; ks < 4; ++ks) qf[ks] = *(const bf16x8*)(qp + ks * 16);
    }

    bf16x8 ones;
#pragma unroll
    for (int e = 0; e < 8; ++e) ones[e] = (bf16_t)1.0f;

    f32x16 z16, o0, o1, l_acc;
#pragma unroll
    for (int i2 = 0; i2 < 16; ++i2) z16[i2] = 0.f;
    o0 = z16; o1 = z16; l_acc = z16;

    // ---- staging: thread t covers rows sr and sr+32, 16B seg = t&7 ----
    const int sr = t >> 3;        // 0..31
    const int sh = (t & 7) * 8;   // element offset
    const bf16_t* kgp = qkv + (rowbase + sr) * 1536 + kcol + sh;
    const bf16_t* vgp = vtg + ((size_t)bh * 64 + sr) * 4096 + sh;
    size_t koff = 0, voff = 0;
    bf16x8 kA, kB, vA, vB;

#define LOADT()                                                   \
    do {                                                          \
        kA = *(const bf16x8*)(kgp + koff);                        \
        kB = *(const bf16x8*)(kgp + koff + (size_t)32 * 1536);    \
        vA = *(const bf16x8*)(vgp + voff);                        \
        vB = *(const bf16x8*)(vgp + voff + (size_t)32 * 4096);    \
        koff += (size_t)64 * 1536;                                \
        voff += 64;                                               \
    } while (0)
#define STORET(bq)                                                \
    do {                                                          \
        *(bf16x8*)&Ks[bq][sr * 68 + sh] = kA;                     \
        *(bf16x8*)&Ks[bq][(sr + 32) * 68 + sh] = kB;              \
        *(bf16x8*)&Vs[bq][sr * 68 + sh] = vA;                     \
        *(bf16x8*)&Vs[bq][(sr + 32) * 68 + sh] = vB;              \
    } while (0)

    // ---- compute one 64-token tile from buf bq (v8 core, verbatim) ----
#define COMPUTE(bq)                                                              \
    do {                                                                         \
        __builtin_amdgcn_s_setprio(1);                                           \
        f32x16 s0, s1;                                                           \
        {                                                                        \
            const bf16x8 k0 = *(const bf16x8*)&Ks[bq][c * 68 + h * 8];           \
            const bf16x8 k1 = *(const bf16x8*)&Ks[bq][(32 + c) * 68 + h * 8];    \
            s0 = MFMA32(k0, qf[0], z16);                                         \
            s1 = MFMA32(k1, qf[0], z16);                                         \
        }                                                                        \
        _Pragma("unroll")                                                        \
        for (int ks = 1; ks < 4; ++ks) {                                         \
            const bf16x8 k0 = *(const bf16x8*)&Ks[bq][c * 68 + ks * 16 + h * 8]; \
            const bf16x8 k1 =                                                    \
                *(const bf16x8*)&Ks[bq][(32 + c) * 68 + ks * 16 + h * 8];        \
            s0 = MFMA32(k0, qf[ks], s0);                                         \
            s1 = MFMA32(k1, qf[ks], s1);                                         \
        }                                                                        \
        __builtin_amdgcn_s_setprio(0);                                           \
        bf16x8 pf[4];                                                            \
        _Pragma("unroll")                                                        \
        for (int tt = 0; tt < 2; ++tt) {                                         \
            const f32x16 sv = tt ? s1 : s0;                                      \
            float ex[16];                                                        \
            _Pragma("unroll")                                                    \
            for (int i3 = 0; i3 < 16; ++i3) ex[i3] = __builtin_amdgcn_exp2f(sv[i3]); \
            unsigned int pk[4][2];                                               \
            _Pragma("unroll")                                                    \
            for (int g = 0; g < 4; ++g) {                                        \
                asm("v_cvt_pk_bf16_f32 %0, %1, %2"                               \
                    : "=v"(pk[g][0]) : "v"(ex[4 * g + 0]), "v"(ex[4 * g + 1]));  \
                asm("v_cvt_pk_bf16_f32 %0, %1, %2"                               \
                    : "=v"(pk[g][1]) : "v"(ex[4 * g + 2]), "v"(ex[4 * g + 3]));  \
            }                                                                    \
            _Pragma("unroll")                                                    \
            for (int k2 = 0; k2 < 2; ++k2) {                                     \
                u32x4 fu;                                                        \
                _Pragma("unroll")                                                \
                for (int cc = 0; cc < 2; ++cc) {                                 \
                    const u32x2 r = __builtin_amdgcn_permlane32_swap(            \
                        pk[2 * k2][cc], pk[2 * k2 + 1][cc], false, false);       \
                    fu[cc] = r[0];                                               \
                    fu[2 + cc] = r[1];                                           \
                }                                                                \
                pf[tt * 2 + k2] = __builtin_bit_cast(bf16x8, fu);                \
            }                                                                    \
        }                                                                        \
        __builtin_amdgcn_s_setprio(1);                                           \
        _Pragma("unroll")                                                        \
        for (int ks = 0; ks < 4; ++ks) {                                         \
            const bf16x8 v0 = *(const bf16x8*)&Vs[bq][c * 68 + ks * 16 + h * 8]; \
            const bf16x8 v1 =                                                    \
                *(const bf16x8*)&Vs[bq][(32 + c) * 68 + ks * 16 + h * 8];        \
            o0 = MFMA32(pf[ks], v0, o0);                                         \
            o1 = MFMA32(pf[ks], v1, o1);                                         \
            l_acc = MFMA32(pf[ks], ones, l_acc);                                 \
        }                                                                        \
        __builtin_amdgcn_s_setprio(0);                                           \
    } while (0)

    // ---- prologue: tile0 -> buf0; tile1 -> regs ----
    LOADT();        // tile 0 -> regs
    STORET(0);      // tile 0 -> buf0 (no reader yet; vmcnt auto-waited)
    LOADT();        // tile 1 -> regs
    __syncthreads();  // buf0 visible to all waves

    for (int it2 = 0; it2 < 32; ++it2) {
        // ---- body A: compute tile 2*it2 from buf0 ----
        STORET(1);                     // tile 2*it2+1 (regs from prev body)
        if (it2 < 31) LOADT();         // tile 2*it2+2 -> regs
        COMPUTE(0);
        __syncthreads();

        // ---- body B: compute tile 2*it2+1 from buf1 ----
        if (it2 < 31) {
            STORET(0);                 // tile 2*it2+2
            LOADT();                   // tile 2*it2+3 -> regs
        }
        COMPUTE(1);
        __syncthreads();
    }
#undef LOADT
#undef STORET
#undef COMPUTE

    // ---- epilogue: row = (reg&3) + 8*(reg>>2) + 4h matches both o and l ----
#pragma unroll
    for (int g = 0; g < 4; ++g) {
#pragma unroll
        for (int r4 = 0; r4 < 4; ++r4) {
            const int reg = 4 * g + r4;
            const int row = r4 + 8 * g + 4 * h;
            const float inv = 1.0f / l_acc[reg];
            bf16_t* op = ao + (rowbase + q0w + row) * 512 + qcol;
            op[c] = (bf16_t)(o0[reg] * inv);
            op[32 + c] = (bf16_t)(o1[reg] * inv);
        }
    }
}

// ---------------------------------------------------------------------------
extern "C" void kernel_launch(void* const* d_in, const int* in_sizes, int n_in,
                              void* d_out, int out_size, void* d_ws, size_t ws_size,
                              hipStream_t stream) {
    const void* x = d_in[0];
    const void* gamma = d_in[1];
    const void* beta = d_in[2];
    const void* Wq = d_in[3];
    const void* Wkv = d_in[4];
    const void* Wo = d_in[5];

    char* wsb = (char*)d_ws;
    int* flag = (int*)wsb;
    bf16_t* xn = (bf16_t*)(wsb + 256);            // 8192*768
    bf16_t* WqkvT = xn + (size_t)8192 * 768;      // 1536*768
    bf16_t* WoT = WqkvT + (size_t)1536 * 768;     // 768*512
    bf16_t* qkv = WoT + (size_t)768 * 512;        // 8192*1536 (V region unused)
    bf16_t* aob = xn;                             // alias: xn dead after QKV gemm
    bf16_t* vtg = (bf16_t*)d_out;                 // scratch until final GEMM

    // 1: LN + weight transposes + dtype flag
    prep_kernel<<<2432, 256, 0, stream>>>(x, gamma, beta, Wq, Wkv, Wo, xn, WqkvT, WoT,
                                          flag);

    // 2: fused QKV projection (Q pre-scaled; V written transposed to vtg)
    qkv_gemm<<<dim3(12, 64), 256, 0, stream>>>(xn, WqkvT, qkv, vtg, 8192, 1536, 768);

    // 3: attention (MFMA32 in-register-P core + dbuf staging, 1 barrier/tile)
    attn_kernel<<<dim3(32, 16), 256, 0, stream>>>(qkv, vtg, aob);

    // 4: output projection
    gemm_bt64<<<dim3(12, 64), 128, 0, stream>>>(aob, WoT, d_out, 8192, 768, 512, flag);
}

// Round 10
// 226.597 us; speedup vs baseline: 1.1316x; 1.0090x over previous
//
#include <hip/hip_runtime.h>
#include <hip/hip_bf16.h>

// x(2,4096,768) -> LN -> QKV proj -> 8-head attention (d=64) -> Wo.
// Inputs fp32 (runtime-detected); internal pipeline bf16.
// B=2, L=4096, DIM=768, HEADS=8, DHEAD=64, INNER=512.
// 4 dispatches: prep (LN + W^T + flag), QKV GEMM (Q pre-scaled, V written
// transposed straight to vtg), attention (v13 VERBATIM — verified 88.4us:
// MFMA32 swapped QK^T, in-register P, dbuf K/V, 1 barrier/tile), output GEMM
// (v15: 256-thr 4-wave blocks, M32xN64 per wave -> 3 waves/SIMD vs 1.5).
// [v14's 128-thr attn had a nondeterministic failure AND its occupancy math
// was wrong (2 waves/SIMD either way, LDS-capped) -> reverted.]

typedef __bf16 bf16_t;
typedef __bf16 bf16x4 __attribute__((ext_vector_type(4)));
typedef __bf16 bf16x8 __attribute__((ext_vector_type(8)));
typedef float f32x4 __attribute__((ext_vector_type(4)));
typedef float f32x16 __attribute__((ext_vector_type(16)));
typedef unsigned int u32x2 __attribute__((ext_vector_type(2)));
typedef unsigned int u32x4 __attribute__((ext_vector_type(4)));

#define MFMA16(a, b, c) __builtin_amdgcn_mfma_f32_16x16x32_bf16((a), (b), (c), 0, 0, 0)
#define MFMA32(a, b, c) __builtin_amdgcn_mfma_f32_32x32x16_bf16((a), (b), (c), 0, 0, 0)

// 0.125 (softmax scale^2) * log2(e): scores come out of QK^T in log2 units.
#define QSCALE 0.18033688011112042f

// async global->LDS, 16 B per lane; LDS dst = wave-uniform base + lane*16.
#define GLDS(gp, lp)                                                          \
    __builtin_amdgcn_global_load_lds(                                         \
        (const __attribute__((address_space(1))) void*)(gp),                  \
        (__attribute__((address_space(3))) void*)(lp), 16, 0, 0)

// ---------------------------------------------------------------------------
// Per-wave input-dtype detect: 1 = fp32, 0 = bf16. 128 L2-hot words.
// ---------------------------------------------------------------------------
__device__ __forceinline__ int detect_f32(const unsigned int* __restrict__ xw) {
    const int l = threadIdx.x & 63;
    int cnt = 0;
#pragma unroll
    for (int j = 0; j < 2; ++j) {
        const unsigned int e = (xw[l * 2 + j] >> 7) & 0xFF;
        cnt += (e >= 100 && e <= 140) ? 1 : 0;
    }
#pragma unroll
    for (int off = 1; off < 64; off <<= 1) cnt += __shfl_xor(cnt, off, 64);
    return cnt < 64;
}

// ---------------------------------------------------------------------------
// prep: blocks 0..2047 = LayerNorm (4 rows each, wave-per-row);
// blocks 2048..2431 = 64x64 transpose tiles of Wq/Wkv/Wo -> bf16 W^T.
// ---------------------------------------------------------------------------
__global__ __launch_bounds__(256) void prep_kernel(
    const void* __restrict__ xv, const void* __restrict__ gv,
    const void* __restrict__ bv, const void* __restrict__ wq,
    const void* __restrict__ wkv, const void* __restrict__ wo,
    bf16_t* __restrict__ xn, bf16_t* __restrict__ WqkvT, bf16_t* __restrict__ WoT,
    int* __restrict__ flag) {
    const int f32 = detect_f32((const unsigned int*)xv);
    const int bid = blockIdx.x;
    const int t = threadIdx.x;
    if (bid == 0 && t == 0) *flag = f32;

    __shared__ bf16_t Ts[64 * 68];

    if (bid < 2048) {
        const int lane = t & 63;
        const int row = bid * 4 + (t >> 6);
        const int c0 = lane * 12;
        float v[12];
        if (f32) {
            const float* xr = (const float*)xv + (size_t)row * 768 + c0;
#pragma unroll
            for (int i = 0; i < 3; ++i) {
                const float4 q = *(const float4*)(xr + i * 4);
                v[i * 4] = q.x; v[i * 4 + 1] = q.y;
                v[i * 4 + 2] = q.z; v[i * 4 + 3] = q.w;
            }
        } else {
            const bf16_t* xr = (const bf16_t*)xv + (size_t)row * 768 + c0;
#pragma unroll
            for (int i = 0; i < 3; ++i) {
                const bf16x4 q = *(const bf16x4*)(xr + i * 4);
#pragma unroll
                for (int j = 0; j < 4; ++j) v[i * 4 + j] = (float)q[j];
            }
        }
        float s = 0.f, sq = 0.f;
#pragma unroll
        for (int j = 0; j < 12; ++j) { s += v[j]; sq += v[j] * v[j]; }
#pragma unroll
        for (int off = 1; off < 64; off <<= 1) {
            s += __shfl_xor(s, off, 64);
            sq += __shfl_xor(sq, off, 64);
        }
        const float mu = s * (1.0f / 768.0f);
        const float var = sq * (1.0f / 768.0f) - mu * mu;
        const float rstd = rsqrtf(var + 1e-5f);

        bf16_t* xo = xn + (size_t)row * 768 + c0;
#pragma unroll
        for (int i = 0; i < 3; ++i) {
            bf16x4 o;
#pragma unroll
            for (int j = 0; j < 4; ++j) {
                const int c = c0 + i * 4 + j;
                const float gc = f32 ? ((const float*)gv)[c] : (float)((const bf16_t*)gv)[c];
                const float bc = f32 ? ((const float*)bv)[c] : (float)((const bf16_t*)bv)[c];
                o[j] = (bf16_t)((v[i * 4 + j] - mu) * rstd * gc + bc);
            }
            *(bf16x4*)(xo + i * 4) = o;
        }
        return;
    }

    int idx = bid - 2048;
    const void* in;
    bf16_t* out;
    int R, C, cx, ry;
    if (idx < 96) {                       // Wq: 768x512 -> WqkvT[0..511][768]
        in = wq; out = WqkvT; R = 768; C = 512;
        cx = idx & 7; ry = idx >> 3;
    } else if (idx < 288) {               // Wkv: 768x1024 -> WqkvT[512..1535][768]
        idx -= 96;
        in = wkv; out = WqkvT + (size_t)512 * 768; R = 768; C = 1024;
        cx = idx & 15; ry = idx >> 4;
    } else {                              // Wo: 512x768 -> WoT[768][512]
        idx -= 288;
        in = wo; out = WoT; R = 512; C = 768;
        cx = idx % 12; ry = idx / 12;
    }
    const int r0 = ry * 64, c0 = cx * 64;
    {
        const int r = t >> 2, c = (t & 3) * 16;
        if (f32) {
            const float* src = (const float*)in + (size_t)(r0 + r) * C + c0 + c;
#pragma unroll
            for (int i = 0; i < 16; i += 4) {
                const float4 q = *(const float4*)(src + i);
                Ts[r * 68 + c + i] = (bf16_t)q.x;
                Ts[r * 68 + c + i + 1] = (bf16_t)q.y;
                Ts[r * 68 + c + i + 2] = (bf16_t)q.z;
                Ts[r * 68 + c + i + 3] = (bf16_t)q.w;
            }
        } else {
            const bf16_t* src = (const bf16_t*)in + (size_t)(r0 + r) * C + c0 + c;
            *(bf16x8*)&Ts[r * 68 + c] = *(const bf16x8*)src;
            *(bf16x8*)&Ts[r * 68 + c + 8] = *(const bf16x8*)(src + 8);
        }
    }
    __syncthreads();
    {
        const int oc = t >> 2, seg = (t & 3) * 16;
        bf16x8 v0, v1;
#pragma unroll
        for (int j = 0; j < 8; ++j) v0[j] = Ts[(seg + j) * 68 + oc];
#pragma unroll
        for (int j = 0; j < 8; ++j) v1[j] = Ts[(seg + 8 + j) * 68 + oc];
        bf16_t* dst = out + (size_t)(c0 + oc) * R + r0 + seg;
        *(bf16x8*)dst = v0;
        *(bf16x8*)(dst + 8) = v1;
    }
}

// ---------------------------------------------------------------------------
// QKV GEMM (m97-style): qkv[M][1536] = xn @ WqkvT^T. 128x128 tile, BK=32,
// global_load_lds width 16. Epilogue: Q cols (<512) scaled by QSCALE; K cols
// written to qkv; V cols (>=1024) written TRANSPOSED to vtg[bh][d][tok].
// ---------------------------------------------------------------------------
__global__ __launch_bounds__(256) void qkv_gemm(const bf16_t* __restrict__ A,
                                                const bf16_t* __restrict__ BT,
                                                bf16_t* __restrict__ qkv,
                                                bf16_t* __restrict__ vtg,
                                                int M, int N, int K) {
    const int m0 = blockIdx.y * 128;
    const int n0 = blockIdx.x * 128;
    __shared__ bf16_t As[128 * 32];
    __shared__ bf16_t Bs[128 * 32];

    const int t = threadIdx.x;
    const int lane = t & 63;
    const int w = t >> 6;
    const int wm = (w >> 1) * 64;
    const int wn = (w & 1) * 64;
    const int quad = lane >> 4;
    const int cl = lane & 15;

    f32x4 acc[4][4];
    const f32x4 z4 = {0.f, 0.f, 0.f, 0.f};
#pragma unroll
    for (int mi = 0; mi < 4; ++mi)
#pragma unroll
        for (int ni = 0; ni < 4; ++ni) acc[mi][ni] = z4;

    const int r0 = lane >> 2;
    const int c0 = (lane & 3) * 8;
    const bf16_t* AgL = A + (size_t)(m0 + w * 32 + r0) * K + c0;
    const bf16_t* AgH = A + (size_t)(m0 + w * 32 + 16 + r0) * K + c0;
    const bf16_t* BgL = BT + (size_t)(n0 + w * 32 + r0) * K + c0;
    const bf16_t* BgH = BT + (size_t)(n0 + w * 32 + 16 + r0) * K + c0;
    bf16_t* AdL = &As[(w * 32) * 32];
    bf16_t* AdH = &As[(w * 32 + 16) * 32];
    bf16_t* BdL = &Bs[(w * 32) * 32];
    bf16_t* BdH = &Bs[(w * 32 + 16) * 32];

    for (int kt = 0; kt < K; kt += 32) {
        __syncthreads();
        GLDS(AgL + kt, AdL);
        GLDS(AgH + kt, AdH);
        GLDS(BgL + kt, BdL);
        GLDS(BgH + kt, BdH);
        __syncthreads();  // drains vmcnt(0): LDS tiles complete

        const int ko = quad * 8;
        bf16x8 af[4], bfr[4];
#pragma unroll
        for (int mi = 0; mi < 4; ++mi)
            af[mi] = *(const bf16x8*)&As[(wm + mi * 16 + cl) * 32 + ko];
#pragma unroll
        for (int ni = 0; ni < 4; ++ni)
            bfr[ni] = *(const bf16x8*)&Bs[(wn + ni * 16 + cl) * 32 + ko];
#pragma unroll
        for (int mi = 0; mi < 4; ++mi)
#pragma unroll
            for (int ni = 0; ni < 4; ++ni)
                acc[mi][ni] = MFMA16(af[mi], bfr[ni], acc[mi][ni]);
    }

    if (n0 >= 1024) {
        // ---- V tile: write transposed to vtg[(b*8+h)*64+d][tok] ----
        const int b = m0 >> 12;
#pragma unroll
        for (int mi = 0; mi < 4; ++mi) {
#pragma unroll
            for (int ni = 0; ni < 4; ++ni) {
                const int tok = (m0 & 4095) + wm + mi * 16 + quad * 4;
                const int dl = n0 + wn + ni * 16 + cl - 1024;   // 0..511
                bf16x4 pk;
#pragma unroll
                for (int r4 = 0; r4 < 4; ++r4) pk[r4] = (bf16_t)acc[mi][ni][r4];
                *(bf16x4*)(vtg + ((size_t)(b * 8 + (dl >> 6)) * 64 + (dl & 63)) * 4096 +
                           tok) = pk;
            }
        }
    } else {
        const float sc = (n0 < 512) ? QSCALE : 1.0f;
#pragma unroll
        for (int mi = 0; mi < 4; ++mi) {
#pragma unroll
            for (int ni = 0; ni < 4; ++ni) {
#pragma unroll
                for (int r4 = 0; r4 < 4; ++r4) {
                    const int row = m0 + wm + mi * 16 + quad * 4 + r4;
                    const int col = n0 + wn + ni * 16 + cl;
                    qkv[(size_t)row * N + col] = (bf16_t)(acc[mi][ni][r4] * sc);
                }
            }
        }
    }
}

// ---------------------------------------------------------------------------
// Output GEMM v15: 256-thread 4-wave blocks, tile M=128 x N=64, BK=32.
// Each wave computes M32xN64 (acc[2][4], 8 MFMA16/K-step). Grid (12,64)=768
// blocks -> 12 waves/CU = 3 waves/SIMD (old 128-thr version was 1.5/SIMD,
// latency-bound). Output fp32 or bf16 per *out_flag.
// ---------------------------------------------------------------------------
__global__ __launch_bounds__(256) void gemm_bt64(const bf16_t* __restrict__ A,
                                                 const bf16_t* __restrict__ BT,
                                                 void* __restrict__ C,
                                                 int M, int N, int K,
                                                 const int* __restrict__ out_flag) {
    const int m0 = blockIdx.y * 128;
    const int n0 = blockIdx.x * 64;
    __shared__ bf16_t As[128 * 32];
    __shared__ bf16_t Bs[64 * 32];

    const int t = threadIdx.x;
    const int lane = t & 63;
    const int w = t >> 6;  // 0..3
    const int quad = lane >> 4;
    const int cl = lane & 15;

    f32x4 acc[2][4];
    const f32x4 z4 = {0.f, 0.f, 0.f, 0.f};
#pragma unroll
    for (int mi = 0; mi < 2; ++mi)
#pragma unroll
        for (int ni = 0; ni < 4; ++ni) acc[mi][ni] = z4;

    const int r0 = lane >> 2;        // 0..15
    const int c0 = (lane & 3) * 8;   // 0/8/16/24
    // A: wave w stages rows [w*32, w*32+32) in two 16-row GLDS
    const bf16_t* AgL = A + (size_t)(m0 + w * 32 + r0) * K + c0;
    const bf16_t* AgH = A + (size_t)(m0 + w * 32 + 16 + r0) * K + c0;
    bf16_t* AdL = &As[(w * 32) * 32];
    bf16_t* AdH = &As[(w * 32 + 16) * 32];
    // B: wave w stages rows [w*16, w*16+16)
    const bf16_t* Bg = BT + (size_t)(n0 + w * 16 + r0) * K + c0;
    bf16_t* Bd = &Bs[(w * 16) * 32];

    for (int kt = 0; kt < K; kt += 32) {
        __syncthreads();
        GLDS(AgL + kt, AdL);
        GLDS(AgH + kt, AdH);
        GLDS(Bg + kt, Bd);
        __syncthreads();  // drains vmcnt(0): LDS tiles complete

        const int ko = quad * 8;
        bf16x8 af[2], bfr[4];
#pragma unroll
        for (int mi = 0; mi < 2; ++mi)
            af[mi] = *(const bf16x8*)&As[(w * 32 + mi * 16 + cl) * 32 + ko];
#pragma unroll
        for (int ni = 0; ni < 4; ++ni)
            bfr[ni] = *(const bf16x8*)&Bs[(ni * 16 + cl) * 32 + ko];
#pragma unroll
        for (int mi = 0; mi < 2; ++mi)
#pragma unroll
            for (int ni = 0; ni < 4; ++ni)
                acc[mi][ni] = MFMA16(af[mi], bfr[ni], acc[mi][ni]);
    }

    const int f32out = *out_flag;
#pragma unroll
    for (int mi = 0; mi < 2; ++mi) {
#pragma unroll
        for (int ni = 0; ni < 4; ++ni) {
#pragma unroll
            for (int r4 = 0; r4 < 4; ++r4) {
                const int row = m0 + w * 32 + mi * 16 + quad * 4 + r4;
                const int col = n0 + ni * 16 + cl;
                if (f32out)
                    ((float*)C)[(size_t)row * N + col] = acc[mi][ni][r4];
                else
                    ((bf16_t*)C)[(size_t)row * N + col] = (bf16_t)acc[mi][ni][r4];
            }
        }
    }
}

// ---------------------------------------------------------------------------
// Flash attention v13 (VERBATIM, verified 88.4us / absmax 1.22e-4):
// 4 waves x 32 q-rows, full token range per block. K/V double-buffered in
// padded [64][68] LDS (34.8 KB, 2 blocks/CU), reg-staged one full compute
// phase ahead, ONE barrier per tile. Swapped QK^T MFMA32; in-register P via
// v_cvt_pk_bf16_f32 + permlane32_swap; l via mfma(P, ones); direct epilogue.
// ---------------------------------------------------------------------------
__global__ __launch_bounds__(256, 2) void attn_kernel(const bf16_t* __restrict__ qkv,
                                                      const bf16_t* __restrict__ vtg,
                                                      bf16_t* __restrict__ ao) {
    const int qt = blockIdx.x;    // 0..31  (128-row q tile)
    const int bh = blockIdx.y;    // 0..15
    const int b = bh >> 3, hd = bh & 7;
    const int q0 = qt * 128;

    __shared__ bf16_t Ks[2][64 * 68];   // [buf][tok][d], stride 68 (136 B)
    __shared__ bf16_t Vs[2][64 * 68];   // [buf][d][tok], stride 68

    const int t = threadIdx.x;
    const int lane = t & 63;
    const int w = t >> 6;         // 0..3: 32-row q subtile
    const int c = lane & 31;
    const int h = lane >> 5;

    const size_t rowbase = (size_t)b * 4096;
    const int qcol = hd * 64;
    const int kcol = 512 + hd * 64;
    const int q0w = q0 + w * 32;

    // ---- Q fragments (B-operand): lane holds Q[q0w+c][ks*16 + 8h .. +7] ----
    bf16x8 qf[4];
    {
        const bf16_t* qp = qkv + (rowbase + q0w + c) * 1536 + qcol + h * 8;
#pragma unroll
        for (int ks = 0; ks < 4; ++ks) qf[ks] = *(const bf16x8*)(qp + ks * 16);
    }

    bf16x8 ones;
#pragma unroll
    for (int e = 0; e < 8; ++e) ones[e] = (bf16_t)1.0f;

    f32x16 z16, o0, o1, l_acc;
#pragma unroll
    for (int i2 = 0; i2 < 16; ++i2) z16[i2] = 0.f;
    o0 = z16; o1 = z16; l_acc = z16;

    // ---- staging: thread t covers rows sr and sr+32, 16B seg = t&7 ----
    const int sr = t >> 3;        // 0..31
    const int sh = (t & 7) * 8;   // element offset
    const bf16_t* kgp = qkv + (rowbase + sr) * 1536 + kcol + sh;
    const bf16_t* vgp = vtg + ((size_t)bh * 64 + sr) * 4096 + sh;
    size_t koff = 0, voff = 0;
    bf16x8 kA, kB, vA, vB;

#define LOADT()                                                   \
    do {                                                          \
        kA = *(const bf16x8*)(kgp + koff);                        \
        kB = *(const bf16x8*)(kgp + koff + (size_t)32 * 1536);    \
        vA = *(const bf16x8*)(vgp + voff);                        \
        vB = *(const bf16x8*)(vgp + voff + (size_t)32 * 4096);    \
        koff += (size_t)64 * 1536;                                \
        voff += 64;                                               \
    } while (0)
#define STORET(bq)                                                \
    do {                                                          \
        *(bf16x8*)&Ks[bq][sr * 68 + sh] = kA;                     \
        *(bf16x8*)&Ks[bq][(sr + 32) * 68 + sh] = kB;              \
        *(bf16x8*)&Vs[bq][sr * 68 + sh] = vA;                     \
        *(bf16x8*)&Vs[bq][(sr + 32) * 68 + sh] = vB;              \
    } while (0)

    // ---- compute one 64-token tile from buf bq (v8 core, verbatim) ----
#define COMPUTE(bq)                                                              \
    do {                                                                         \
        __builtin_amdgcn_s_setprio(1);                                           \
        f32x16 s0, s1;                                                           \
        {                                                                        \
            const bf16x8 k0 = *(const bf16x8*)&Ks[bq][c * 68 + h * 8];           \
            const bf16x8 k1 = *(const bf16x8*)&Ks[bq][(32 + c) * 68 + h * 8];    \
            s0 = MFMA32(k0, qf[0], z16);                                         \
            s1 = MFMA32(k1, qf[0], z16);                                         \
        }                                                                        \
        _Pragma("unroll")                                                        \
        for (int ks = 1; ks < 4; ++ks) {                                         \
            const bf16x8 k0 = *(const bf16x8*)&Ks[bq][c * 68 + ks * 16 + h * 8]; \
            const bf16x8 k1 =                                                    \
                *(const bf16x8*)&Ks[bq][(32 + c) * 68 + ks * 16 + h * 8];        \
            s0 = MFMA32(k0, qf[ks], s0);                                         \
            s1 = MFMA32(k1, qf[ks], s1);                                         \
        }                                                                        \
        __builtin_amdgcn_s_setprio(0);                                           \
        bf16x8 pf[4];                                                            \
        _Pragma("unroll")                                                        \
        for (int tt = 0; tt < 2; ++tt) {                                         \
            const f32x16 sv = tt ? s1 : s0;                                      \
            float ex[16];                                                        \
            _Pragma("unroll")                                                    \
            for (int i3 = 0; i3 < 16; ++i3) ex[i3] = __builtin_amdgcn_exp2f(sv[i3]); \
            unsigned int pk[4][2];                                               \
            _Pragma("unroll")                                                    \
            for (int g = 0; g < 4; ++g) {                                        \
                asm("v_cvt_pk_bf16_f32 %0, %1, %2"                               \
                    : "=v"(pk[g][0]) : "v"(ex[4 * g + 0]), "v"(ex[4 * g + 1]));  \
                asm("v_cvt_pk_bf16_f32 %0, %1, %2"                               \
                    : "=v"(pk[g][1]) : "v"(ex[4 * g + 2]), "v"(ex[4 * g + 3]));  \
            }                                                                    \
            _Pragma("unroll")                                                    \
            for (int k2 = 0; k2 < 2; ++k2) {                                     \
                u32x4 fu;                                                        \
                _Pragma("unroll")                                                \
                for (int cc = 0; cc < 2; ++cc) {                                 \
                    const u32x2 r = __builtin_amdgcn_permlane32_swap(            \
                        pk[2 * k2][cc], pk[2 * k2 + 1][cc], false, false);       \
                    fu[cc] = r[0];                                               \
                    fu[2 + cc] = r[1];                                           \
                }                                                                \
                pf[tt * 2 + k2] = __builtin_bit_cast(bf16x8, fu);                \
            }                                                                    \
        }                                                                        \
        __builtin_amdgcn_s_setprio(1);                                           \
        _Pragma("unroll")                                                        \
        for (int ks = 0; ks < 4; ++ks) {                                         \
            const bf16x8 v0 = *(const bf16x8*)&Vs[bq][c * 68 + ks * 16 + h * 8]; \
            const bf16x8 v1 =                                                    \
                *(const bf16x8*)&Vs[bq][(32 + c) * 68 + ks * 16 + h * 8];        \
            o0 = MFMA32(pf[ks], v0, o0);                                         \
            o1 = MFMA32(pf[ks], v1, o1);                                         \
            l_acc = MFMA32(pf[ks], ones, l_acc);                                 \
        }                                                                        \
        __builtin_amdgcn_s_setprio(0);                                           \
    } while (0)

    // ---- prologue: tile0 -> buf0; tile1 -> regs ----
    LOADT();        // tile 0 -> regs
    STORET(0);      // tile 0 -> buf0 (no reader yet; vmcnt auto-waited)
    LOADT();        // tile 1 -> regs
    __syncthreads();  // buf0 visible to all waves

    for (int it2 = 0; it2 < 32; ++it2) {
        // ---- body A: compute tile 2*it2 from buf0 ----
        STORET(1);                     // tile 2*it2+1 (regs from prev body)
        if (it2 < 31) LOADT();         // tile 2*it2+2 -> regs
        COMPUTE(0);
        __syncthreads();

        // ---- body B: compute tile 2*it2+1 from buf1 ----
        if (it2 < 31) {
            STORET(0);                 // tile 2*it2+2
            LOADT();                   // tile 2*it2+3 -> regs
        }
        COMPUTE(1);
        __syncthreads();
    }
#undef LOADT
#undef STORET
#undef COMPUTE

    // ---- epilogue: row = (reg&3) + 8*(reg>>2) + 4h matches both o and l ----
#pragma unroll
    for (int g = 0; g < 4; ++g) {
#pragma unroll
        for (int r4 = 0; r4 < 4; ++r4) {
            const int reg = 4 * g + r4;
            const int row = r4 + 8 * g + 4 * h;
            const float inv = 1.0f / l_acc[reg];
            bf16_t* op = ao + (rowbase + q0w + row) * 512 + qcol;
            op[c] = (bf16_t)(o0[reg] * inv);
            op[32 + c] = (bf16_t)(o1[reg] * inv);
        }
    }
}

// ---------------------------------------------------------------------------
extern "C" void kernel_launch(void* const* d_in, const int* in_sizes, int n_in,
                              void* d_out, int out_size, void* d_ws, size_t ws_size,
                              hipStream_t stream) {
    const void* x = d_in[0];
    const void* gamma = d_in[1];
    const void* beta = d_in[2];
    const void* Wq = d_in[3];
    const void* Wkv = d_in[4];
    const void* Wo = d_in[5];

    char* wsb = (char*)d_ws;
    int* flag = (int*)wsb;
    bf16_t* xn = (bf16_t*)(wsb + 256);            // 8192*768
    bf16_t* WqkvT = xn + (size_t)8192 * 768;      // 1536*768
    bf16_t* WoT = WqkvT + (size_t)1536 * 768;     // 768*512
    bf16_t* qkv = WoT + (size_t)768 * 512;        // 8192*1536 (V region unused)
    bf16_t* aob = xn;                             // alias: xn dead after QKV gemm
    bf16_t* vtg = (bf16_t*)d_out;                 // scratch until final GEMM

    // 1: LN + weight transposes + dtype flag
    prep_kernel<<<2432, 256, 0, stream>>>(x, gamma, beta, Wq, Wkv, Wo, xn, WqkvT, WoT,
                                          flag);

    // 2: fused QKV projection (Q pre-scaled; V written transposed to vtg)
    qkv_gemm<<<dim3(12, 64), 256, 0, stream>>>(xn, WqkvT, qkv, vtg, 8192, 1536, 768);

    // 3: attention (v13 verified core)
    attn_kernel<<<dim3(32, 16), 256, 0, stream>>>(qkv, vtg, aob);

    // 4: output projection (4-wave blocks, 3 waves/SIMD)
    gemm_bt64<<<dim3(12, 64), 256, 0, stream>>>(aob, WoT, d_out, 8192, 768, 512, flag);
}